// Round 4
// baseline (508.589 us; speedup 1.0000x reference)
//
#include <hip/hip_runtime.h>
#include <hip/hip_bf16.h>
#include <stdint.h>

typedef __attribute__((ext_vector_type(8))) short bf16x8;
typedef __attribute__((ext_vector_type(4))) float f32x4;
typedef __attribute__((ext_vector_type(16))) float f32x16;
typedef unsigned short u16;
typedef unsigned int u32;
typedef const __attribute__((address_space(1))) u32* gp_t;
typedef __attribute__((address_space(3))) u32* lp_t;

#define HD 128
#define NH 16
#define SEQ 2048
#define PASTN 2048
#define FULLS 4096
#define DM 2048

__device__ __forceinline__ u16 f2b(float f){
  union { float f; u32 u; } v; v.f = f;
  return (u16)((v.u + 0x7fffu + ((v.u >> 16) & 1u)) >> 16);
}
__device__ __forceinline__ float b2f(u16 b){
  union { u32 u; float f; } v; v.u = ((u32)b) << 16;
  return v.f;
}
__device__ __forceinline__ u32 cvtpk(float lo, float hi){
  u32 r; asm("v_cvt_pk_bf16_f32 %0, %1, %2" : "=v"(r) : "v"(lo), "v"(hi)); return r;
}

// ---------------- fp32 -> bf16 convert (vectorized) ----------------
__global__ void k_conv(const float* __restrict__ src, u16* __restrict__ dst, int n4){
  int i = blockIdx.x * blockDim.x + threadIdx.x;
  int stride = gridDim.x * blockDim.x;
  for (; i < n4; i += stride){
    float4 v = ((const float4*)src)[i];
    ushort4 o = { f2b(v.x), f2b(v.y), f2b(v.z), f2b(v.w) };
    ((ushort4*)dst)[i] = o;
  }
}

// -------- past_k: fp32 copy to out k-region rows 0..2047 + bf16 to kb --------
__global__ void k_past_k(const float* __restrict__ pk, float* __restrict__ outk,
                         u16* __restrict__ kb, int n4){
  int i = blockIdx.x * blockDim.x + threadIdx.x;
  int stride = gridDim.x * blockDim.x;
  for (; i < n4; i += stride){
    int g = i * 4;
    int c = g & 127;
    int r = g >> 7;
    int bh = r >> 11;
    int s = r & 2047;
    long dst = ((long)bh * FULLS + s) * HD + c;
    float4 v = ((const float4*)pk)[i];
    *(float4*)(outk + dst) = v;
    ushort4 o = { f2b(v.x), f2b(v.y), f2b(v.z), f2b(v.w) };
    *(ushort4*)(kb + dst) = o;
  }
}

// -------- past_v: fp32 copy + bf16 TRANSPOSED into vtb[bh][d][key] --------
__global__ void k_past_v(const float* __restrict__ pv, float* __restrict__ outv,
                         u16* __restrict__ vtb){
  __shared__ float tile[32][33];
  int bh = blockIdx.z;
  int d0 = blockIdx.x * 32;
  int s0 = blockIdx.y * 32;
  int tx = threadIdx.x, ty = threadIdx.y;
  const float* src = pv + (long)bh * PASTN * HD;
  float* dstv = outv + (long)bh * FULLS * HD;
#pragma unroll
  for (int k = 0; k < 4; k++){
    int si = ty + 8 * k;
    float v = src[(long)(s0 + si) * HD + d0 + tx];
    dstv[(long)(s0 + si) * HD + d0 + tx] = v;
    tile[si][tx] = v;
  }
  __syncthreads();
  u16* dstt = vtb + (long)bh * HD * FULLS;
#pragma unroll
  for (int k = 0; k < 4; k++){
    int di = ty + 8 * k;
    dstt[(long)(d0 + di) * FULLS + (s0 + tx)] = f2b(tile[tx][di]);
  }
}

// ---------------- bt-GEMM: C = A(MxK) * B(NxK)^T, bf16 in ----------------
// 1-D grid of 512 blocks, XCD-chunk swizzled: each XCD gets 4 contiguous
// M-tile rows x all 16 N-tiles -> A-panel (2MB) L2-resident per XCD.
template<int MODE>
__global__ void k_gemm(const u16* __restrict__ A, const u16* __restrict__ Bm,
                       float* __restrict__ outf, u16* __restrict__ outb,
                       int M, int N, int K)
{
  __shared__ u16 As[128 * 64];
  __shared__ u16 Bs[128 * 64];
  const int tid = threadIdx.x;
  const int w = tid >> 6, l = tid & 63;
  const int d = blockIdx.x;
  const int lid = ((d & 7) << 6) + (d >> 3);   // bijective: 512 = 8 * 64
  const int m0 = (lid >> 4) * 128, n0 = (lid & 15) * 128;
  const int wr = w >> 1, wc = w & 1;
  const int lr = l & 15;
  const int lkb = (l >> 4) * 16;
  f32x4 acc[4][4] = {};

  for (int kt = 0; kt < K; kt += 64){
#pragma unroll
    for (int it = 0; it < 4; it++){
      int Pw = it * 4096 + w * 1024;
      int P = Pw + l * 16;
      int row = P >> 7, cb = P & 127;
      const u16* ga = A + (long)(m0 + row) * K + kt + (cb >> 1);
      __builtin_amdgcn_global_load_lds((gp_t)(const void*)ga, (lp_t)(void*)((char*)As + Pw), 16, 0, 0);
      const u16* gb = Bm + (long)(n0 + row) * K + kt + (cb >> 1);
      __builtin_amdgcn_global_load_lds((gp_t)(const void*)gb, (lp_t)(void*)((char*)Bs + Pw), 16, 0, 0);
    }
    __syncthreads();
#pragma unroll
    for (int kk = 0; kk < 2; kk++){
      bf16x8 af[4], bf[4];
#pragma unroll
      for (int i = 0; i < 4; i++){
        af[i] = *(const bf16x8*)((const char*)As + (wr * 64 + i * 16 + lr) * 128 + kk * 64 + lkb);
        bf[i] = *(const bf16x8*)((const char*)Bs + (wc * 64 + i * 16 + lr) * 128 + kk * 64 + lkb);
      }
#pragma unroll
      for (int i = 0; i < 4; i++)
#pragma unroll
        for (int j = 0; j < 4; j++)
          acc[i][j] = __builtin_amdgcn_mfma_f32_16x16x32_bf16(af[i], bf[j], acc[i][j], 0, 0, 0);
    }
    __syncthreads();
  }

  const int rbase = m0 + wr * 64 + ((l >> 4) << 2);
  const int cbase = n0 + wc * 64 + lr;
#pragma unroll
  for (int i = 0; i < 4; i++){
#pragma unroll
    for (int j = 0; j < 4; j++){
      const int nn = cbase + j * 16;
      if (MODE == 2){
        const int mm = rbase + i * 16;
        const int b = mm >> 11, s = mm & 2047;
        const int h = nn >> 7, dd = nn & 127;
        const int bh = b * NH + h;
        ushort4 pk = { f2b(acc[i][j][0]), f2b(acc[i][j][1]), f2b(acc[i][j][2]), f2b(acc[i][j][3]) };
        *(ushort4*)(outb + ((long)bh * HD + dd) * FULLS + PASTN + s) = pk;
#pragma unroll
        for (int r = 0; r < 4; r++){
          long idx = ((long)bh * FULLS + PASTN + s + r) * HD + dd;
          outf[idx] = acc[i][j][r];
        }
      } else {
#pragma unroll
        for (int r = 0; r < 4; r++){
          const int mm = rbase + i * 16 + r;
          float v = acc[i][j][r];
          if (MODE == 0){
            const int b = mm >> 11, s = mm & 2047;
            const int h = nn >> 7, dd = nn & 127;
            outb[(((long)(b * NH + h)) * SEQ + s) * HD + dd] = f2b(v);
          } else if (MODE == 1){
            const int b = mm >> 11, s = mm & 2047;
            const int h = nn >> 7, dd = nn & 127;
            long idx = (((long)(b * NH + h)) * FULLS + PASTN + s) * HD + dd;
            outb[idx] = f2b(v);
            outf[idx] = v;
          } else {
            outf[(long)mm * N + nn] = v;
          }
        }
      }
    }
  }
}

// ------- flash attention: 4 waves x 32 q-rows, 32x32x16 MFMA, swapped QK^T,
// ------- in-register softmax, KV dbuf swizzled LDS, XCD-chunked block map.
__global__ __launch_bounds__(256, 2)
void k_attn(const u16* __restrict__ qb, const u16* __restrict__ kb,
            const u16* __restrict__ vtb, u16* __restrict__ ab)
{
  __shared__ u16 Ks[2][64 * 128];    // [key][d] 256B rows, 16-slot swizzle
  __shared__ u16 Vs[2][128 * 64];    // [d][key] 128B rows, 8-slot swizzle
  const int tid = threadIdx.x, w = tid >> 6, l = tid & 63;
  const int lq = l & 31, hi = l >> 5;
  // XCD-chunk swizzle: XCD k owns lid in [k*64,(k+1)*64) = bh 4k..4k+3, all q0b.
  // The 16 q-blocks of one bh stream the same K/V tiles -> per-XCD L2 hits.
  const int dd0 = blockIdx.x;
  const int lid = ((dd0 & 7) << 6) + (dd0 >> 3);
  const int bh = lid >> 4;
  const int q0b = (lid & 15) << 7;
  const int qbase = q0b + w * 32;
  const int qpos = PASTN + qbase + lq;
  const u16* qhead = qb + (long)bh * SEQ * HD;
  const u16* khead = kb + (long)bh * FULLS * HD;
  const u16* vhead = vtb + (long)bh * HD * FULLS;

  const float qscale = 0.08838834764831845f * 1.4426950408889634f;
  bf16x8 qf[8];
#pragma unroll
  for (int ks = 0; ks < 8; ks++){
    bf16x8 tq = *(const bf16x8*)(qhead + (long)(qbase + lq) * HD + ks * 16 + hi * 8);
#pragma unroll
    for (int j = 0; j < 8; j++) tq[j] = (short)f2b(b2f((u16)tq[j]) * qscale);
    qf[ks] = tq;
  }

  f32x16 acc[4] = {};
  float m_run = -1e30f, l_run = 0.f;

  const int ntiles = (PASTN + q0b + 128) >> 6;
  const int qmaxw = PASTN + qbase + 31;

  auto stage = [&](int buf, int t){
    const char* ktile = (const char*)(khead + (long)t * 64 * HD);
#pragma unroll
    for (int it = 0; it < 4; it++){
      int base = it * 4096 + w * 1024;
      int P = base + l * 16;
      int ksrc = P ^ (((P >> 8) & 15) << 4);
      __builtin_amdgcn_global_load_lds((gp_t)(const void*)(ktile + ksrc),
                                       (lp_t)(void*)((char*)Ks[buf] + base), 16, 0, 0);
      int row = P >> 7;
      int cb = (P & 127) ^ ((row & 7) << 4);
      const u16* gv = vhead + (long)row * FULLS + t * 64 + (cb >> 1);
      __builtin_amdgcn_global_load_lds((gp_t)(const void*)gv,
                                       (lp_t)(void*)((char*)Vs[buf] + base), 16, 0, 0);
    }
  };

  stage(0, 0);
  __syncthreads();

  int cur = 0;
  for (int t = 0; t < ntiles; t++){
    if (t + 1 < ntiles) stage(cur ^ 1, t + 1);
    const int kvb = t * 64;
    if (kvb <= qmaxw){
      // ---- S^T = K Q
      const char* Kc = (const char*)Ks[cur];
      f32x16 s0 = {}, s1 = {};
      const int kswz = (lq & 15) << 4;
      __builtin_amdgcn_s_setprio(1);
#pragma unroll
      for (int ks = 0; ks < 8; ks++){
        int c = ks * 32 + hi * 16;
        bf16x8 kf0 = *(const bf16x8*)(Kc + lq * 256 + (c ^ kswz));
        bf16x8 kf1 = *(const bf16x8*)(Kc + (32 + lq) * 256 + (c ^ kswz));
        s0 = __builtin_amdgcn_mfma_f32_32x32x16_bf16(kf0, qf[ks], s0, 0, 0, 0);
        s1 = __builtin_amdgcn_mfma_f32_32x32x16_bf16(kf1, qf[ks], s1, 0, 0, 0);
      }
      __builtin_amdgcn_s_setprio(0);

      // ---- causal mask
      if (kvb + 63 > PASTN + qbase){
#pragma unroll
        for (int r = 0; r < 16; r++){
          int key = kvb + (r & 3) + 8 * (r >> 2) + 4 * hi;
          if (key > qpos) s0[r] = -1e30f;
          if (key + 32 > qpos) s1[r] = -1e30f;
        }
      }

      // ---- in-register row max
      float a0[8];
#pragma unroll
      for (int i = 0; i < 8; i++)
        a0[i] = fmaxf(fmaxf(s0[i], s0[i + 8]), fmaxf(s1[i], s1[i + 8]));
      float a1[4];
#pragma unroll
      for (int i = 0; i < 4; i++) a1[i] = fmaxf(a0[i], a0[i + 4]);
      float mx = fmaxf(fmaxf(a1[0], a1[1]), fmaxf(a1[2], a1[3]));
      mx = fmaxf(mx, __shfl_xor(mx, 32));

      // ---- defer-max rescale (rare)
      if (!__all(mx <= m_run + 8.f)){
        float mnew = fmaxf(m_run, mx);
        float corr = __builtin_exp2f(m_run - mnew);
        m_run = mnew; l_run *= corr;
#pragma unroll
        for (int r = 0; r < 16; r++){
          int qlr = (r & 3) + 8 * (r >> 2) + 4 * hi;
          float cr = __shfl(corr, qlr);
#pragma unroll
          for (int d2 = 0; d2 < 4; d2++) acc[d2][r] *= cr;
        }
      }

      // ---- P = exp2(S - m), row sum
      float rs = 0.f;
#pragma unroll
      for (int r = 0; r < 16; r++){
        s0[r] = __builtin_exp2f(s0[r] - m_run); rs += s0[r];
        s1[r] = __builtin_exp2f(s1[r] - m_run); rs += s1[r];
      }
      rs += __shfl_xor(rs, 32);
      l_run += rs;

      // ---- pack P into A-fragments
      bf16x8 pfrag[4];
#pragma unroll
      for (int kb2 = 0; kb2 < 2; kb2++){
        f32x16 sp = kb2 ? s1 : s0;
#pragma unroll
        for (int half = 0; half < 2; half++){
          float p0 = sp[half * 8 + 0], p1 = sp[half * 8 + 1];
          float p2 = sp[half * 8 + 2], p3 = sp[half * 8 + 3];
          float p4 = sp[half * 8 + 4], p5 = sp[half * 8 + 5];
          float p6 = sp[half * 8 + 6], p7 = sp[half * 8 + 7];
          u32 x0 = cvtpk(p0, p1), x1 = cvtpk(p2, p3);
          u32 y0 = cvtpk(p4, p5), y1 = cvtpk(p6, p7);
          u32 sx0 = (u32)__shfl_xor((int)x0, 32);
          u32 sx1 = (u32)__shfl_xor((int)x1, 32);
          u32 sy0 = (u32)__shfl_xor((int)y0, 32);
          u32 sy1 = (u32)__shfl_xor((int)y1, 32);
          union { u32 wd[4]; bf16x8 v; } F;
          F.wd[0] = hi ? sy0 : x0;
          F.wd[1] = hi ? sy1 : x1;
          F.wd[2] = hi ? y0 : sx0;
          F.wd[3] = hi ? y1 : sx1;
          pfrag[kb2 * 2 + half] = F.v;
        }
      }

      // ---- O += P V
      const char* Vc = (const char*)Vs[cur];
      __builtin_amdgcn_s_setprio(1);
#pragma unroll
      for (int ks2 = 0; ks2 < 4; ks2++){
        int c = ks2 * 32 + hi * 16;
#pragma unroll
        for (int d2 = 0; d2 < 4; d2++){
          int row = d2 * 32 + lq;
          bf16x8 vf = *(const bf16x8*)(Vc + row * 128 + (c ^ ((row & 7) << 4)));
          acc[d2] = __builtin_amdgcn_mfma_f32_32x32x16_bf16(pfrag[ks2], vf, acc[d2], 0, 0, 0);
        }
      }
      __builtin_amdgcn_s_setprio(0);
    }
    __syncthreads();
    cur ^= 1;
  }

  // ---- epilogue: normalize, write ab (B,S,DM) bf16
  float inv = 1.0f / l_run;
  const int b = bh >> 4, h = bh & 15;
#pragma unroll
  for (int r = 0; r < 16; r++){
    int qlr = (r & 3) + 8 * (r >> 2) + 4 * hi;
    float ir = __shfl(inv, qlr);
    long rowbase = ((long)b * SEQ + (qbase + qlr)) * DM + h * HD;
#pragma unroll
    for (int d2 = 0; d2 < 4; d2++)
      ab[rowbase + d2 * 32 + lq] = f2b(acc[d2][r] * ir);
  }
}

extern "C" void kernel_launch(void* const* d_in, const int* in_sizes, int n_in,
                              void* d_out, int out_size, void* d_ws, size_t ws_size,
                              hipStream_t stream) {
  const float* x      = (const float*)d_in[0];
  const float* past_k = (const float*)d_in[1];
  const float* past_v = (const float*)d_in[2];
  const float* Wq     = (const float*)d_in[3];
  const float* Wk     = (const float*)d_in[4];
  const float* Wv     = (const float*)d_in[5];
  const float* Wo     = (const float*)d_in[6];

  float* out  = (float*)d_out;
  float* outk = out + 8388608;       // B*S*DM
  float* outv = out + 25165824;      // + B*NH*FULLS*HD

  char* ws = (char*)d_ws;
  u16* wqb = (u16*)ws;
  u16* wkb = (u16*)(ws + 8388608);
  u16* wvb = (u16*)(ws + 16777216);
  u16* wob = (u16*)(ws + 25165824);
  u16* xb  = (u16*)(ws + 33554432);
  u16* qb  = (u16*)(ws + 50331648);
  u16* kb  = (u16*)(ws + 67108864);
  u16* vtb = (u16*)(ws + 100663296);
  u16* ab  = xb;                     // alias: x consumed before attn writes

  k_conv<<<1024, 256, 0, stream>>>(x,  xb,  2097152);
  k_conv<<<1024, 256, 0, stream>>>(Wq, wqb, 1048576);
  k_conv<<<1024, 256, 0, stream>>>(Wk, wkb, 1048576);
  k_conv<<<1024, 256, 0, stream>>>(Wv, wvb, 1048576);
  k_conv<<<1024, 256, 0, stream>>>(Wo, wob, 1048576);
  k_past_k<<<2048, 256, 0, stream>>>(past_k, outk, kb, 2097152);
  k_past_v<<<dim3(4, 64, 32), dim3(32, 8), 0, stream>>>(past_v, outv, vtb);

  k_gemm<0><<<512, 256, 0, stream>>>(xb, wqb, nullptr, qb, 4096, 2048, 2048);
  k_gemm<1><<<512, 256, 0, stream>>>(xb, wkb, outk, kb, 4096, 2048, 2048);
  k_gemm<2><<<512, 256, 0, stream>>>(xb, wvb, outv, vtb, 4096, 2048, 2048);

  k_attn<<<512, 256, 0, stream>>>(qb, kb, vtb, ab);

  k_gemm<3><<<512, 256, 0, stream>>>(ab, wob, out, nullptr, 4096, 2048, 2048);
}

// Round 5
// 492.748 us; speedup vs baseline: 1.0321x; 1.0321x over previous
//
#include <hip/hip_runtime.h>
#include <hip/hip_bf16.h>
#include <stdint.h>

typedef __attribute__((ext_vector_type(8))) short bf16x8;
typedef __attribute__((ext_vector_type(4))) float f32x4;
typedef __attribute__((ext_vector_type(16))) float f32x16;
typedef unsigned short u16;
typedef unsigned int u32;
typedef const __attribute__((address_space(1))) u32* gp_t;
typedef __attribute__((address_space(3))) u32* lp_t;

#define HD 128
#define NH 16
#define SEQ 2048
#define PASTN 2048
#define FULLS 4096
#define DM 2048

__device__ __forceinline__ u16 f2b(float f){
  union { float f; u32 u; } v; v.f = f;
  return (u16)((v.u + 0x7fffu + ((v.u >> 16) & 1u)) >> 16);
}
__device__ __forceinline__ float b2f(u16 b){
  union { u32 u; float f; } v; v.u = ((u32)b) << 16;
  return v.f;
}
__device__ __forceinline__ u32 cvtpk(float lo, float hi){
  u32 r; asm("v_cvt_pk_bf16_f32 %0, %1, %2" : "=v"(r) : "v"(lo), "v"(hi)); return r;
}

// ---------------- fp32 -> bf16 convert (vectorized) ----------------
__global__ void k_conv(const float* __restrict__ src, u16* __restrict__ dst, int n4){
  int i = blockIdx.x * blockDim.x + threadIdx.x;
  int stride = gridDim.x * blockDim.x;
  for (; i < n4; i += stride){
    float4 v = ((const float4*)src)[i];
    ushort4 o = { f2b(v.x), f2b(v.y), f2b(v.z), f2b(v.w) };
    ((ushort4*)dst)[i] = o;
  }
}

// -------- past_k: fp32 copy to out k-region rows 0..2047 + bf16 to kb --------
__global__ void k_past_k(const float* __restrict__ pk, float* __restrict__ outk,
                         u16* __restrict__ kb, int n4){
  int i = blockIdx.x * blockDim.x + threadIdx.x;
  int stride = gridDim.x * blockDim.x;
  for (; i < n4; i += stride){
    int g = i * 4;
    int c = g & 127;
    int r = g >> 7;
    int bh = r >> 11;
    int s = r & 2047;
    long dst = ((long)bh * FULLS + s) * HD + c;
    float4 v = ((const float4*)pk)[i];
    *(float4*)(outk + dst) = v;
    ushort4 o = { f2b(v.x), f2b(v.y), f2b(v.z), f2b(v.w) };
    *(ushort4*)(kb + dst) = o;
  }
}

// -------- past_v: fp32 copy + bf16 TRANSPOSED into vtb[bh][d][key] --------
__global__ void k_past_v(const float* __restrict__ pv, float* __restrict__ outv,
                         u16* __restrict__ vtb){
  __shared__ float tile[32][33];
  int bh = blockIdx.z;
  int d0 = blockIdx.x * 32;
  int s0 = blockIdx.y * 32;
  int tx = threadIdx.x, ty = threadIdx.y;
  const float* src = pv + (long)bh * PASTN * HD;
  float* dstv = outv + (long)bh * FULLS * HD;
#pragma unroll
  for (int k = 0; k < 4; k++){
    int si = ty + 8 * k;
    float v = src[(long)(s0 + si) * HD + d0 + tx];
    dstv[(long)(s0 + si) * HD + d0 + tx] = v;
    tile[si][tx] = v;
  }
  __syncthreads();
  u16* dstt = vtb + (long)bh * HD * FULLS;
#pragma unroll
  for (int k = 0; k < 4; k++){
    int di = ty + 8 * k;
    dstt[(long)(d0 + di) * FULLS + (s0 + tx)] = f2b(tile[tx][di]);
  }
}

// ---------------- bt-GEMM: C = A(MxK) * B(NxK)^T, bf16 in ----------------
// 2-D grid (16,32) — round-3 configuration (1-D XCD swizzle regressed it).
template<int MODE>
__global__ void k_gemm(const u16* __restrict__ A, const u16* __restrict__ Bm,
                       float* __restrict__ outf, u16* __restrict__ outb,
                       int M, int N, int K)
{
  __shared__ u16 As[128 * 64];
  __shared__ u16 Bs[128 * 64];
  const int tid = threadIdx.x;
  const int w = tid >> 6, l = tid & 63;
  const int m0 = blockIdx.y * 128, n0 = blockIdx.x * 128;
  const int wr = w >> 1, wc = w & 1;
  const int lr = l & 15;
  const int lkb = (l >> 4) * 16;
  f32x4 acc[4][4] = {};

  for (int kt = 0; kt < K; kt += 64){
#pragma unroll
    for (int it = 0; it < 4; it++){
      int Pw = it * 4096 + w * 1024;
      int P = Pw + l * 16;
      int row = P >> 7, cb = P & 127;
      const u16* ga = A + (long)(m0 + row) * K + kt + (cb >> 1);
      __builtin_amdgcn_global_load_lds((gp_t)(const void*)ga, (lp_t)(void*)((char*)As + Pw), 16, 0, 0);
      const u16* gb = Bm + (long)(n0 + row) * K + kt + (cb >> 1);
      __builtin_amdgcn_global_load_lds((gp_t)(const void*)gb, (lp_t)(void*)((char*)Bs + Pw), 16, 0, 0);
    }
    __syncthreads();
#pragma unroll
    for (int kk = 0; kk < 2; kk++){
      bf16x8 af[4], bf[4];
#pragma unroll
      for (int i = 0; i < 4; i++){
        af[i] = *(const bf16x8*)((const char*)As + (wr * 64 + i * 16 + lr) * 128 + kk * 64 + lkb);
        bf[i] = *(const bf16x8*)((const char*)Bs + (wc * 64 + i * 16 + lr) * 128 + kk * 64 + lkb);
      }
#pragma unroll
      for (int i = 0; i < 4; i++)
#pragma unroll
        for (int j = 0; j < 4; j++)
          acc[i][j] = __builtin_amdgcn_mfma_f32_16x16x32_bf16(af[i], bf[j], acc[i][j], 0, 0, 0);
    }
    __syncthreads();
  }

  const int rbase = m0 + wr * 64 + ((l >> 4) << 2);
  const int cbase = n0 + wc * 64 + lr;
#pragma unroll
  for (int i = 0; i < 4; i++){
#pragma unroll
    for (int j = 0; j < 4; j++){
      const int nn = cbase + j * 16;
      if (MODE == 2){
        const int mm = rbase + i * 16;
        const int b = mm >> 11, s = mm & 2047;
        const int h = nn >> 7, dd = nn & 127;
        const int bh = b * NH + h;
        ushort4 pk = { f2b(acc[i][j][0]), f2b(acc[i][j][1]), f2b(acc[i][j][2]), f2b(acc[i][j][3]) };
        *(ushort4*)(outb + ((long)bh * HD + dd) * FULLS + PASTN + s) = pk;
#pragma unroll
        for (int r = 0; r < 4; r++){
          long idx = ((long)bh * FULLS + PASTN + s + r) * HD + dd;
          outf[idx] = acc[i][j][r];
        }
      } else {
#pragma unroll
        for (int r = 0; r < 4; r++){
          const int mm = rbase + i * 16 + r;
          float v = acc[i][j][r];
          if (MODE == 0){
            const int b = mm >> 11, s = mm & 2047;
            const int h = nn >> 7, dd = nn & 127;
            outb[(((long)(b * NH + h)) * SEQ + s) * HD + dd] = f2b(v);
          } else if (MODE == 1){
            const int b = mm >> 11, s = mm & 2047;
            const int h = nn >> 7, dd = nn & 127;
            long idx = (((long)(b * NH + h)) * FULLS + PASTN + s) * HD + dd;
            outb[idx] = f2b(v);
            outf[idx] = v;
          } else {
            outf[(long)mm * N + nn] = v;
          }
        }
      }
    }
  }
}

// ------- flash attention: 4 waves x 32 q-rows, 32x32x16 MFMA, swapped QK^T,
// ------- in-register softmax, KV dbuf swizzled LDS.
// Block map: XCD-chunked (4 bh per XCD, L2-resident KV) AND tail-balanced:
// within an XCD, j=32a+2b+c -> bh_local=2a+c, q0b=(a^c)?15-b:b, so both
// (2i,2i+1) and (j,j+32) CU-pairings sum to the mean 98 tiles.
__global__ __launch_bounds__(256, 2)
void k_attn(const u16* __restrict__ qb, const u16* __restrict__ kb,
            const u16* __restrict__ vtb, u16* __restrict__ ab)
{
  __shared__ u16 Ks[2][64 * 128];    // [key][d] 256B rows, 16-slot swizzle
  __shared__ u16 Vs[2][128 * 64];    // [d][key] 128B rows, 8-slot swizzle
  const int tid = threadIdx.x, w = tid >> 6, l = tid & 63;
  const int lq = l & 31, hi = l >> 5;
  const int dd0 = blockIdx.x;
  const int xcd = dd0 & 7;
  const int j   = dd0 >> 3;               // [0,64) within XCD
  const int ja = j >> 5, jb = (j >> 1) & 15, jc = j & 1;
  const int bh  = xcd * 4 + 2 * ja + jc;
  const int q0b = ((ja ^ jc) ? (15 - jb) : jb) << 7;
  const int qbase = q0b + w * 32;
  const int qpos = PASTN + qbase + lq;
  const u16* qhead = qb + (long)bh * SEQ * HD;
  const u16* khead = kb + (long)bh * FULLS * HD;
  const u16* vhead = vtb + (long)bh * HD * FULLS;

  const float qscale = 0.08838834764831845f * 1.4426950408889634f;
  bf16x8 qf[8];
#pragma unroll
  for (int ks = 0; ks < 8; ks++){
    bf16x8 tq = *(const bf16x8*)(qhead + (long)(qbase + lq) * HD + ks * 16 + hi * 8);
#pragma unroll
    for (int jj = 0; jj < 8; jj++) tq[jj] = (short)f2b(b2f((u16)tq[jj]) * qscale);
    qf[ks] = tq;
  }

  f32x16 acc[4] = {};
  float m_run = -1e30f, l_run = 0.f;

  const int ntiles = (PASTN + q0b + 128) >> 6;
  const int qmaxw = PASTN + qbase + 31;

  auto stage = [&](int buf, int t){
    const char* ktile = (const char*)(khead + (long)t * 64 * HD);
#pragma unroll
    for (int it = 0; it < 4; it++){
      int base = it * 4096 + w * 1024;
      int P = base + l * 16;
      int ksrc = P ^ (((P >> 8) & 15) << 4);
      __builtin_amdgcn_global_load_lds((gp_t)(const void*)(ktile + ksrc),
                                       (lp_t)(void*)((char*)Ks[buf] + base), 16, 0, 0);
      int row = P >> 7;
      int cb = (P & 127) ^ ((row & 7) << 4);
      const u16* gv = vhead + (long)row * FULLS + t * 64 + (cb >> 1);
      __builtin_amdgcn_global_load_lds((gp_t)(const void*)gv,
                                       (lp_t)(void*)((char*)Vs[buf] + base), 16, 0, 0);
    }
  };

  stage(0, 0);
  __syncthreads();

  int cur = 0;
  for (int t = 0; t < ntiles; t++){
    if (t + 1 < ntiles) stage(cur ^ 1, t + 1);
    const int kvb = t * 64;
    if (kvb <= qmaxw){
      // ---- S^T = K Q
      const char* Kc = (const char*)Ks[cur];
      f32x16 s0 = {}, s1 = {};
      const int kswz = (lq & 15) << 4;
      __builtin_amdgcn_s_setprio(1);
#pragma unroll
      for (int ks = 0; ks < 8; ks++){
        int c = ks * 32 + hi * 16;
        bf16x8 kf0 = *(const bf16x8*)(Kc + lq * 256 + (c ^ kswz));
        bf16x8 kf1 = *(const bf16x8*)(Kc + (32 + lq) * 256 + (c ^ kswz));
        s0 = __builtin_amdgcn_mfma_f32_32x32x16_bf16(kf0, qf[ks], s0, 0, 0, 0);
        s1 = __builtin_amdgcn_mfma_f32_32x32x16_bf16(kf1, qf[ks], s1, 0, 0, 0);
      }
      __builtin_amdgcn_s_setprio(0);

      // ---- causal mask
      if (kvb + 63 > PASTN + qbase){
#pragma unroll
        for (int r = 0; r < 16; r++){
          int key = kvb + (r & 3) + 8 * (r >> 2) + 4 * hi;
          if (key > qpos) s0[r] = -1e30f;
          if (key + 32 > qpos) s1[r] = -1e30f;
        }
      }

      // ---- in-register row max
      float a0[8];
#pragma unroll
      for (int i = 0; i < 8; i++)
        a0[i] = fmaxf(fmaxf(s0[i], s0[i + 8]), fmaxf(s1[i], s1[i + 8]));
      float a1[4];
#pragma unroll
      for (int i = 0; i < 4; i++) a1[i] = fmaxf(a0[i], a0[i + 4]);
      float mx = fmaxf(fmaxf(a1[0], a1[1]), fmaxf(a1[2], a1[3]));
      mx = fmaxf(mx, __shfl_xor(mx, 32));

      // ---- defer-max rescale (rare)
      if (!__all(mx <= m_run + 8.f)){
        float mnew = fmaxf(m_run, mx);
        float corr = __builtin_exp2f(m_run - mnew);
        m_run = mnew; l_run *= corr;
#pragma unroll
        for (int r = 0; r < 16; r++){
          int qlr = (r & 3) + 8 * (r >> 2) + 4 * hi;
          float cr = __shfl(corr, qlr);
#pragma unroll
          for (int d2 = 0; d2 < 4; d2++) acc[d2][r] *= cr;
        }
      }

      // ---- P = exp2(S - m), row sum
      float rs = 0.f;
#pragma unroll
      for (int r = 0; r < 16; r++){
        s0[r] = __builtin_exp2f(s0[r] - m_run); rs += s0[r];
        s1[r] = __builtin_exp2f(s1[r] - m_run); rs += s1[r];
      }
      rs += __shfl_xor(rs, 32);
      l_run += rs;

      // ---- pack P into A-fragments
      bf16x8 pfrag[4];
#pragma unroll
      for (int kb2 = 0; kb2 < 2; kb2++){
        f32x16 sp = kb2 ? s1 : s0;
#pragma unroll
        for (int half = 0; half < 2; half++){
          float p0 = sp[half * 8 + 0], p1 = sp[half * 8 + 1];
          float p2 = sp[half * 8 + 2], p3 = sp[half * 8 + 3];
          float p4 = sp[half * 8 + 4], p5 = sp[half * 8 + 5];
          float p6 = sp[half * 8 + 6], p7 = sp[half * 8 + 7];
          u32 x0 = cvtpk(p0, p1), x1 = cvtpk(p2, p3);
          u32 y0 = cvtpk(p4, p5), y1 = cvtpk(p6, p7);
          u32 sx0 = (u32)__shfl_xor((int)x0, 32);
          u32 sx1 = (u32)__shfl_xor((int)x1, 32);
          u32 sy0 = (u32)__shfl_xor((int)y0, 32);
          u32 sy1 = (u32)__shfl_xor((int)y1, 32);
          union { u32 wd[4]; bf16x8 v; } F;
          F.wd[0] = hi ? sy0 : x0;
          F.wd[1] = hi ? sy1 : x1;
          F.wd[2] = hi ? y0 : sx0;
          F.wd[3] = hi ? y1 : sx1;
          pfrag[kb2 * 2 + half] = F.v;
        }
      }

      // ---- O += P V
      const char* Vc = (const char*)Vs[cur];
      __builtin_amdgcn_s_setprio(1);
#pragma unroll
      for (int ks2 = 0; ks2 < 4; ks2++){
        int c = ks2 * 32 + hi * 16;
#pragma unroll
        for (int d2 = 0; d2 < 4; d2++){
          int row = d2 * 32 + lq;
          bf16x8 vf = *(const bf16x8*)(Vc + row * 128 + (c ^ ((row & 7) << 4)));
          acc[d2] = __builtin_amdgcn_mfma_f32_32x32x16_bf16(pfrag[ks2], vf, acc[d2], 0, 0, 0);
        }
      }
      __builtin_amdgcn_s_setprio(0);
    }
    __syncthreads();
    cur ^= 1;
  }

  // ---- epilogue: normalize, write ab (B,S,DM) bf16
  float inv = 1.0f / l_run;
  const int b = bh >> 4, h = bh & 15;
#pragma unroll
  for (int r = 0; r < 16; r++){
    int qlr = (r & 3) + 8 * (r >> 2) + 4 * hi;
    float ir = __shfl(inv, qlr);
    long rowbase = ((long)b * SEQ + (qbase + qlr)) * DM + h * HD;
#pragma unroll
    for (int d2 = 0; d2 < 4; d2++)
      ab[rowbase + d2 * 32 + lq] = f2b(acc[d2][r] * ir);
  }
}

extern "C" void kernel_launch(void* const* d_in, const int* in_sizes, int n_in,
                              void* d_out, int out_size, void* d_ws, size_t ws_size,
                              hipStream_t stream) {
  const float* x      = (const float*)d_in[0];
  const float* past_k = (const float*)d_in[1];
  const float* past_v = (const float*)d_in[2];
  const float* Wq     = (const float*)d_in[3];
  const float* Wk     = (const float*)d_in[4];
  const float* Wv     = (const float*)d_in[5];
  const float* Wo     = (const float*)d_in[6];

  float* out  = (float*)d_out;
  float* outk = out + 8388608;       // B*S*DM
  float* outv = out + 25165824;      // + B*NH*FULLS*HD

  char* ws = (char*)d_ws;
  u16* wqb = (u16*)ws;
  u16* wkb = (u16*)(ws + 8388608);
  u16* wvb = (u16*)(ws + 16777216);
  u16* wob = (u16*)(ws + 25165824);
  u16* xb  = (u16*)(ws + 33554432);
  u16* qb  = (u16*)(ws + 50331648);
  u16* kb  = (u16*)(ws + 67108864);
  u16* vtb = (u16*)(ws + 100663296);
  u16* ab  = xb;                     // alias: x consumed before attn writes

  k_conv<<<1024, 256, 0, stream>>>(x,  xb,  2097152);
  k_conv<<<1024, 256, 0, stream>>>(Wq, wqb, 1048576);
  k_conv<<<1024, 256, 0, stream>>>(Wk, wkb, 1048576);
  k_conv<<<1024, 256, 0, stream>>>(Wv, wvb, 1048576);
  k_conv<<<1024, 256, 0, stream>>>(Wo, wob, 1048576);
  k_past_k<<<2048, 256, 0, stream>>>(past_k, outk, kb, 2097152);
  k_past_v<<<dim3(4, 64, 32), dim3(32, 8), 0, stream>>>(past_v, outv, vtb);

  dim3 gg(16, 32);
  k_gemm<0><<<gg, 256, 0, stream>>>(xb, wqb, nullptr, qb, 4096, 2048, 2048);
  k_gemm<1><<<gg, 256, 0, stream>>>(xb, wkb, outk, kb, 4096, 2048, 2048);
  k_gemm<2><<<gg, 256, 0, stream>>>(xb, wvb, outv, vtb, 4096, 2048, 2048);

  k_attn<<<512, 256, 0, stream>>>(qb, kb, vtb, ab);

  k_gemm<3><<<gg, 256, 0, stream>>>(ab, wob, out, nullptr, 4096, 2048, 2048);
}

// Round 6
// 469.540 us; speedup vs baseline: 1.0832x; 1.0494x over previous
//
#include <hip/hip_runtime.h>
#include <hip/hip_bf16.h>
#include <stdint.h>

typedef __attribute__((ext_vector_type(8))) short bf16x8;
typedef __attribute__((ext_vector_type(4))) float f32x4;
typedef __attribute__((ext_vector_type(16))) float f32x16;
typedef unsigned short u16;
typedef unsigned int u32;
typedef const __attribute__((address_space(1))) u32* gp_t;
typedef __attribute__((address_space(3))) u32* lp_t;

#define HD 128
#define NH 16
#define SEQ 2048
#define PASTN 2048
#define FULLS 4096
#define DM 2048

__device__ __forceinline__ u16 f2b(float f){
  union { float f; u32 u; } v; v.f = f;
  return (u16)((v.u + 0x7fffu + ((v.u >> 16) & 1u)) >> 16);
}
__device__ __forceinline__ float b2f(u16 b){
  union { u32 u; float f; } v; v.u = ((u32)b) << 16;
  return v.f;
}
__device__ __forceinline__ u32 cvtpk(float lo, float hi){
  u32 r; asm("v_cvt_pk_bf16_f32 %0, %1, %2" : "=v"(r) : "v"(lo), "v"(hi)); return r;
}
__device__ __forceinline__ f32x16 zero16(){ f32x16 z = {}; return z; }

// ---------------- fp32 -> bf16 convert (vectorized) ----------------
__global__ void k_conv(const float* __restrict__ src, u16* __restrict__ dst, int n4){
  int i = blockIdx.x * blockDim.x + threadIdx.x;
  int stride = gridDim.x * blockDim.x;
  for (; i < n4; i += stride){
    float4 v = ((const float4*)src)[i];
    ushort4 o = { f2b(v.x), f2b(v.y), f2b(v.z), f2b(v.w) };
    ((ushort4*)dst)[i] = o;
  }
}

// -------- past_k: fp32 copy to out k-region rows 0..2047 + bf16 to kb --------
__global__ void k_past_k(const float* __restrict__ pk, float* __restrict__ outk,
                         u16* __restrict__ kb, int n4){
  int i = blockIdx.x * blockDim.x + threadIdx.x;
  int stride = gridDim.x * blockDim.x;
  for (; i < n4; i += stride){
    int g = i * 4;
    int c = g & 127;
    int r = g >> 7;
    int bh = r >> 11;
    int s = r & 2047;
    long dst = ((long)bh * FULLS + s) * HD + c;
    float4 v = ((const float4*)pk)[i];
    *(float4*)(outk + dst) = v;
    ushort4 o = { f2b(v.x), f2b(v.y), f2b(v.z), f2b(v.w) };
    *(ushort4*)(kb + dst) = o;
  }
}

// -------- past_v: fp32 copy + bf16 TRANSPOSED into vtb[bh][d][key] --------
__global__ void k_past_v(const float* __restrict__ pv, float* __restrict__ outv,
                         u16* __restrict__ vtb){
  __shared__ float tile[32][33];
  int bh = blockIdx.z;
  int d0 = blockIdx.x * 32;
  int s0 = blockIdx.y * 32;
  int tx = threadIdx.x, ty = threadIdx.y;
  const float* src = pv + (long)bh * PASTN * HD;
  float* dstv = outv + (long)bh * FULLS * HD;
#pragma unroll
  for (int k = 0; k < 4; k++){
    int si = ty + 8 * k;
    float v = src[(long)(s0 + si) * HD + d0 + tx];
    dstv[(long)(s0 + si) * HD + d0 + tx] = v;
    tile[si][tx] = v;
  }
  __syncthreads();
  u16* dstt = vtb + (long)bh * HD * FULLS;
#pragma unroll
  for (int k = 0; k < 4; k++){
    int di = ty + 8 * k;
    dstt[(long)(d0 + di) * FULLS + (s0 + tx)] = f2b(tile[tx][di]);
  }
}

// ---------------- bt-GEMM: C = A(MxK) * B(NxK)^T, bf16 in ----------------
template<int MODE>
__global__ void k_gemm(const u16* __restrict__ A, const u16* __restrict__ Bm,
                       float* __restrict__ outf, u16* __restrict__ outb,
                       int M, int N, int K)
{
  __shared__ u16 As[128 * 64];
  __shared__ u16 Bs[128 * 64];
  const int tid = threadIdx.x;
  const int w = tid >> 6, l = tid & 63;
  const int m0 = blockIdx.y * 128, n0 = blockIdx.x * 128;
  const int wr = w >> 1, wc = w & 1;
  const int lr = l & 15;
  const int lkb = (l >> 4) * 16;
  f32x4 acc[4][4] = {};

  for (int kt = 0; kt < K; kt += 64){
#pragma unroll
    for (int it = 0; it < 4; it++){
      int Pw = it * 4096 + w * 1024;
      int P = Pw + l * 16;
      int row = P >> 7, cb = P & 127;
      const u16* ga = A + (long)(m0 + row) * K + kt + (cb >> 1);
      __builtin_amdgcn_global_load_lds((gp_t)(const void*)ga, (lp_t)(void*)((char*)As + Pw), 16, 0, 0);
      const u16* gb = Bm + (long)(n0 + row) * K + kt + (cb >> 1);
      __builtin_amdgcn_global_load_lds((gp_t)(const void*)gb, (lp_t)(void*)((char*)Bs + Pw), 16, 0, 0);
    }
    __syncthreads();
#pragma unroll
    for (int kk = 0; kk < 2; kk++){
      bf16x8 af[4], bf[4];
#pragma unroll
      for (int i = 0; i < 4; i++){
        af[i] = *(const bf16x8*)((const char*)As + (wr * 64 + i * 16 + lr) * 128 + kk * 64 + lkb);
        bf[i] = *(const bf16x8*)((const char*)Bs + (wc * 64 + i * 16 + lr) * 128 + kk * 64 + lkb);
      }
#pragma unroll
      for (int i = 0; i < 4; i++)
#pragma unroll
        for (int j = 0; j < 4; j++)
          acc[i][j] = __builtin_amdgcn_mfma_f32_16x16x32_bf16(af[i], bf[j], acc[i][j], 0, 0, 0);
    }
    __syncthreads();
  }

  const int rbase = m0 + wr * 64 + ((l >> 4) << 2);
  const int cbase = n0 + wc * 64 + lr;
#pragma unroll
  for (int i = 0; i < 4; i++){
#pragma unroll
    for (int j = 0; j < 4; j++){
      const int nn = cbase + j * 16;
      if (MODE == 2){
        const int mm = rbase + i * 16;
        const int b = mm >> 11, s = mm & 2047;
        const int h = nn >> 7, dd = nn & 127;
        const int bh = b * NH + h;
        ushort4 pk = { f2b(acc[i][j][0]), f2b(acc[i][j][1]), f2b(acc[i][j][2]), f2b(acc[i][j][3]) };
        *(ushort4*)(outb + ((long)bh * HD + dd) * FULLS + PASTN + s) = pk;
#pragma unroll
        for (int r = 0; r < 4; r++){
          long idx = ((long)bh * FULLS + PASTN + s + r) * HD + dd;
          outf[idx] = acc[i][j][r];
        }
      } else {
#pragma unroll
        for (int r = 0; r < 4; r++){
          const int mm = rbase + i * 16 + r;
          float v = acc[i][j][r];
          if (MODE == 0){
            const int b = mm >> 11, s = mm & 2047;
            const int h = nn >> 7, dd = nn & 127;
            outb[(((long)(b * NH + h)) * SEQ + s) * HD + dd] = f2b(v);
          } else if (MODE == 1){
            const int b = mm >> 11, s = mm & 2047;
            const int h = nn >> 7, dd = nn & 127;
            long idx = (((long)(b * NH + h)) * FULLS + PASTN + s) * HD + dd;
            outb[idx] = f2b(v);
            outf[idx] = v;
          } else {
            outf[(long)mm * N + nn] = v;
          }
        }
      }
    }
  }
}

// ------- flash attention: 4 waves x 32 q-rows, 32x32x16 MFMA, swapped QK^T,
// ------- in-register softmax, T15 2-state pipeline (softmax(t-1) || QKT(t)),
// ------- precomputed LDS addrs (buffer/row/d2 as ds offset immediates),
// ------- permlane32_swap pack/reduce, XCD-chunked tail-balanced block map.
__global__ __launch_bounds__(256, 2)
void k_attn(const u16* __restrict__ qb, const u16* __restrict__ kb,
            const u16* __restrict__ vtb, u16* __restrict__ ab)
{
  __shared__ u16 Ks[2][64 * 128];    // [key][d] 256B rows, 16-slot swizzle
  __shared__ u16 Vs[2][128 * 64];    // [d][key] 128B rows, 8-slot swizzle
  const int tid = threadIdx.x, w = tid >> 6, l = tid & 63;
  const int lq = l & 31, hi = l >> 5;
  const int dd0 = blockIdx.x;
  const int xcd = dd0 & 7;
  const int j   = dd0 >> 3;
  const int ja = j >> 5, jb = (j >> 1) & 15, jc = j & 1;
  const int bh  = xcd * 4 + 2 * ja + jc;
  const int q0b = ((ja ^ jc) ? (15 - jb) : jb) << 7;
  const int qbase = q0b + w * 32;
  const int qpos = PASTN + qbase + lq;
  const u16* qhead = qb + (long)bh * SEQ * HD;
  const u16* khead = kb + (long)bh * FULLS * HD;
  const u16* vhead = vtb + (long)bh * HD * FULLS;

  // Q fragments, prescaled by 1/sqrt(HD)*log2(e)
  const float qscale = 0.08838834764831845f * 1.4426950408889634f;
  bf16x8 qf[8];
#pragma unroll
  for (int ks = 0; ks < 8; ks++){
    bf16x8 tq = *(const bf16x8*)(qhead + (long)(qbase + lq) * HD + ks * 16 + hi * 8);
#pragma unroll
    for (int jj = 0; jj < 8; jj++) tq[jj] = (short)f2b(b2f((u16)tq[jj]) * qscale);
    qf[ks] = tq;
  }

  // -------- precomputed LDS read pointers (lane-const; buf/row/d2 -> imm) ----
  const int kswz = (lq & 15) << 4;
  const int vswz = (lq & 7) << 4;
  const char* kaddr[8];
#pragma unroll
  for (int ks = 0; ks < 8; ks++)
    kaddr[ks] = (const char*)Ks + lq * 256 + ((ks * 32 + hi * 16) ^ kswz);
  const char* vaddr[4];
#pragma unroll
  for (int ks2 = 0; ks2 < 4; ks2++)
    vaddr[ks2] = (const char*)Vs + lq * 128 + ((ks2 * 32 + hi * 16) ^ vswz);

  // -------- precomputed global staging byte offsets (lane-const) ------------
  int ksrcoff[4], vsrcoff[4];
#pragma unroll
  for (int it = 0; it < 4; it++){
    int P = it * 4096 + w * 1024 + l * 16;
    ksrcoff[it] = P ^ (((P >> 8) & 15) << 4);
    int row = P >> 7;
    int cb = (P & 127) ^ ((row & 7) << 4);
    vsrcoff[it] = row * 8192 + cb;
  }

  auto stageK = [&](int t, int bufo){
    const char* src = (const char*)khead + ((long)t << 14);
    char* dstb = (char*)Ks + bufo + w * 1024;
#pragma unroll
    for (int it = 0; it < 4; it++)
      __builtin_amdgcn_global_load_lds((gp_t)(const void*)(src + ksrcoff[it]),
                                       (lp_t)(void*)(dstb + it * 4096), 16, 0, 0);
  };
  auto stageV = [&](int t, int bufo){
    const char* src = (const char*)vhead + ((long)t << 7);
    char* dstb = (char*)Vs + bufo + w * 1024;
#pragma unroll
    for (int it = 0; it < 4; it++)
      __builtin_amdgcn_global_load_lds((gp_t)(const void*)(src + vsrcoff[it]),
                                       (lp_t)(void*)(dstb + it * 4096), 16, 0, 0);
  };

  f32x16 acc[4] = {};
  float m_run = -1e30f, l_run = 0.f;
  const int ntiles = (PASTN + q0b + 128) >> 6;   // always even

  // finish softmax of the tile held in (sp0,sp1) and accumulate PV from vbufo
  auto finishPV = [&](f32x16& sp0, f32x16& sp1, int vbufo){
    float a0[8];
#pragma unroll
    for (int i = 0; i < 8; i++)
      a0[i] = fmaxf(fmaxf(sp0[i], sp0[i + 8]), fmaxf(sp1[i], sp1[i + 8]));
    float mx = fmaxf(fmaxf(fmaxf(a0[0], a0[1]), fmaxf(a0[2], a0[3])),
                     fmaxf(fmaxf(a0[4], a0[5]), fmaxf(a0[6], a0[7])));
    { float xa = mx, xb = mx;
      asm("v_permlane32_swap_b32 %0, %1" : "+v"(xa), "+v"(xb));
      mx = fmaxf(xa, xb); }

    if (!__all(mx <= m_run + 8.f)){
      float mnew = fmaxf(m_run, mx);
      float corr = __builtin_exp2f(m_run - mnew);
      m_run = mnew; l_run *= corr;
#pragma unroll
      for (int r = 0; r < 16; r++){
        int qlr = (r & 3) + 8 * (r >> 2) + 4 * hi;
        float cr = __shfl(corr, qlr);
#pragma unroll
        for (int d2 = 0; d2 < 4; d2++) acc[d2][r] *= cr;
      }
    }

    float rs = 0.f;
#pragma unroll
    for (int r = 0; r < 16; r++){
      sp0[r] = __builtin_exp2f(sp0[r] - m_run); rs += sp0[r];
      sp1[r] = __builtin_exp2f(sp1[r] - m_run); rs += sp1[r];
    }
    { float ra = rs, rb = rs;
      asm("v_permlane32_swap_b32 %0, %1" : "+v"(ra), "+v"(rb));
      l_run += ra + rb; }

    // pack P -> A-fragments via permlane32_swap (both outputs per swap)
    bf16x8 pfrag[4];
#pragma unroll
    for (int kb2 = 0; kb2 < 2; kb2++){
      const f32x16& sp = kb2 ? sp1 : sp0;
#pragma unroll
      for (int half = 0; half < 2; half++){
        const int h8 = half * 8;
        u32 A0 = cvtpk(sp[h8 + 0], sp[h8 + 1]);
        u32 A1 = cvtpk(sp[h8 + 2], sp[h8 + 3]);
        u32 B0 = cvtpk(sp[h8 + 4], sp[h8 + 5]);
        u32 B1 = cvtpk(sp[h8 + 6], sp[h8 + 7]);
        asm("v_permlane32_swap_b32 %0, %1" : "+v"(A0), "+v"(B0));
        asm("v_permlane32_swap_b32 %0, %1" : "+v"(A1), "+v"(B1));
        union { u32 wd[4]; bf16x8 v; } F;
        F.wd[0] = A0; F.wd[1] = A1; F.wd[2] = B0; F.wd[3] = B1;
        pfrag[kb2 * 2 + half] = F.v;
      }
    }

    __builtin_amdgcn_s_setprio(1);
#pragma unroll
    for (int ks2 = 0; ks2 < 4; ks2++)
#pragma unroll
      for (int d2 = 0; d2 < 4; d2++){
        bf16x8 vf = *(const bf16x8*)(vaddr[ks2] + vbufo + d2 * 4096);
        acc[d2] = __builtin_amdgcn_mfma_f32_32x32x16_bf16(pfrag[ks2], vf, acc[d2], 0, 0, 0);
      }
    __builtin_amdgcn_s_setprio(0);
  };

#define QKT_MASK(T_, BUFC_, SC0_, SC1_)                                        \
  {                                                                            \
    SC0_ = zero16(); SC1_ = zero16();                                          \
    __builtin_amdgcn_s_setprio(1);                                             \
    _Pragma("unroll")                                                          \
    for (int ks = 0; ks < 8; ks++){                                            \
      bf16x8 kf0 = *(const bf16x8*)(kaddr[ks] + (BUFC_));                      \
      bf16x8 kf1 = *(const bf16x8*)(kaddr[ks] + (BUFC_) + 8192);               \
      SC0_ = __builtin_amdgcn_mfma_f32_32x32x16_bf16(kf0, qf[ks], SC0_, 0,0,0);\
      SC1_ = __builtin_amdgcn_mfma_f32_32x32x16_bf16(kf1, qf[ks], SC1_, 0,0,0);\
    }                                                                          \
    __builtin_amdgcn_s_setprio(0);                                             \
    const int kvb_ = (T_) * 64;                                                \
    if (kvb_ + 63 > PASTN + qbase){                                            \
      _Pragma("unroll")                                                        \
      for (int r = 0; r < 16; r++){                                            \
        int key = kvb_ + (r & 3) + 8 * (r >> 2) + 4 * hi;                      \
        if (key > qpos) SC0_[r] = -1e30f;                                      \
        if (key + 32 > qpos) SC1_[r] = -1e30f;                                 \
      }                                                                        \
    }                                                                          \
  }

#define STEP(T_, BUFC_, SP0_, SP1_, SC0_, SC1_)                                \
  {                                                                            \
    if ((T_) + 1 < ntiles) stageK((T_) + 1, (BUFC_) ^ 16384);                  \
    QKT_MASK(T_, BUFC_, SC0_, SC1_);                                           \
    finishPV(SP0_, SP1_, (BUFC_) ^ 16384);                                     \
    __syncthreads();                                                           \
    if ((T_) + 1 < ntiles) stageV((T_) + 1, (BUFC_) ^ 16384);                  \
  }

  f32x16 PA0, PA1, PB0, PB1;

  stageK(0, 0); stageV(0, 0);
  __syncthreads();

  // t = 0 (no previous tile to finish)
  stageK(1, 16384);
  QKT_MASK(0, 0, PA0, PA1);
  __syncthreads();
  stageV(1, 16384);

  for (int t = 1; t + 2 < ntiles; t += 2){
    STEP(t,     16384, PA0, PA1, PB0, PB1);
    STEP(t + 1, 0,     PB0, PB1, PA0, PA1);
  }
  STEP(ntiles - 1, 16384, PA0, PA1, PB0, PB1);
  finishPV(PB0, PB1, 16384);

#undef STEP
#undef QKT_MASK

  // ---- epilogue: normalize, write ab (B,S,DM) bf16
  float inv = 1.0f / l_run;
  const int b = bh >> 4, h = bh & 15;
#pragma unroll
  for (int r = 0; r < 16; r++){
    int qlr = (r & 3) + 8 * (r >> 2) + 4 * hi;
    float ir = __shfl(inv, qlr);
    long rowbase = ((long)b * SEQ + (qbase + qlr)) * DM + h * HD;
#pragma unroll
    for (int d2 = 0; d2 < 4; d2++)
      ab[rowbase + d2 * 32 + lq] = f2b(acc[d2][r] * ir);
  }
}

extern "C" void kernel_launch(void* const* d_in, const int* in_sizes, int n_in,
                              void* d_out, int out_size, void* d_ws, size_t ws_size,
                              hipStream_t stream) {
  const float* x      = (const float*)d_in[0];
  const float* past_k = (const float*)d_in[1];
  const float* past_v = (const float*)d_in[2];
  const float* Wq     = (const float*)d_in[3];
  const float* Wk     = (const float*)d_in[4];
  const float* Wv     = (const float*)d_in[5];
  const float* Wo     = (const float*)d_in[6];

  float* out  = (float*)d_out;
  float* outk = out + 8388608;       // B*S*DM
  float* outv = out + 25165824;      // + B*NH*FULLS*HD

  char* ws = (char*)d_ws;
  u16* wqb = (u16*)ws;
  u16* wkb = (u16*)(ws + 8388608);
  u16* wvb = (u16*)(ws + 16777216);
  u16* wob = (u16*)(ws + 25165824);
  u16* xb  = (u16*)(ws + 33554432);
  u16* qb  = (u16*)(ws + 50331648);
  u16* kb  = (u16*)(ws + 67108864);
  u16* vtb = (u16*)(ws + 100663296);
  u16* ab  = xb;                     // alias: x consumed before attn writes

  k_conv<<<1024, 256, 0, stream>>>(x,  xb,  2097152);
  k_conv<<<1024, 256, 0, stream>>>(Wq, wqb, 1048576);
  k_conv<<<1024, 256, 0, stream>>>(Wk, wkb, 1048576);
  k_conv<<<1024, 256, 0, stream>>>(Wv, wvb, 1048576);
  k_conv<<<1024, 256, 0, stream>>>(Wo, wob, 1048576);
  k_past_k<<<2048, 256, 0, stream>>>(past_k, outk, kb, 2097152);
  k_past_v<<<dim3(4, 64, 32), dim3(32, 8), 0, stream>>>(past_v, outv, vtb);

  dim3 gg(16, 32);
  k_gemm<0><<<gg, 256, 0, stream>>>(xb, wqb, nullptr, qb, 4096, 2048, 2048);
  k_gemm<1><<<gg, 256, 0, stream>>>(xb, wkb, outk, kb, 4096, 2048, 2048);
  k_gemm<2><<<gg, 256, 0, stream>>>(xb, wvb, outv, vtb, 4096, 2048, 2048);

  k_attn<<<512, 256, 0, stream>>>(qb, kb, vtb, ab);

  k_gemm<3><<<gg, 256, 0, stream>>>(ab, wob, out, nullptr, 4096, 2048, 2048);
}

// Round 7
// 416.965 us; speedup vs baseline: 1.2197x; 1.1261x over previous
//
#include <hip/hip_runtime.h>
#include <hip/hip_bf16.h>
#include <stdint.h>

typedef __attribute__((ext_vector_type(8))) short bf16x8;
typedef __attribute__((ext_vector_type(4))) float f32x4;
typedef __attribute__((ext_vector_type(16))) float f32x16;
typedef unsigned short u16;
typedef unsigned int u32;
typedef const __attribute__((address_space(1))) u32* gp_t;
typedef __attribute__((address_space(3))) u32* lp_t;

#define HD 128
#define NH 16
#define SEQ 2048
#define PASTN 2048
#define FULLS 4096
#define DM 2048

__device__ __forceinline__ u16 f2b(float f){
  union { float f; u32 u; } v; v.f = f;
  return (u16)((v.u + 0x7fffu + ((v.u >> 16) & 1u)) >> 16);
}
__device__ __forceinline__ float b2f(u16 b){
  union { u32 u; float f; } v; v.u = ((u32)b) << 16;
  return v.f;
}
__device__ __forceinline__ u32 cvtpk(float lo, float hi){
  u32 r; asm("v_cvt_pk_bf16_f32 %0, %1, %2" : "=v"(r) : "v"(lo), "v"(hi)); return r;
}
__device__ __forceinline__ f32x16 zero16(){ f32x16 z = {}; return z; }

// ------- fused fp32->bf16 convert of x, Wq, Wk, Wv, Wo (one launch) -------
__global__ void k_conv5(const float* __restrict__ sx,
                        const float* __restrict__ s1, const float* __restrict__ s2,
                        const float* __restrict__ s3, const float* __restrict__ s4,
                        u16* __restrict__ dx,
                        u16* __restrict__ d1, u16* __restrict__ d2,
                        u16* __restrict__ d3, u16* __restrict__ d4)
{
  const int total = 2097152 + 4 * 1048576;
  int i = blockIdx.x * blockDim.x + threadIdx.x;
  int stride = gridDim.x * blockDim.x;
  for (; i < total; i += stride){
    const float* s; u16* d; int off;
    if (i < 2097152){ s = sx; d = dx; off = i; }
    else {
      int t = i - 2097152;
      int seg = t >> 20; off = t & 1048575;
      s = (seg == 0) ? s1 : (seg == 1) ? s2 : (seg == 2) ? s3 : s4;
      d = (seg == 0) ? d1 : (seg == 1) ? d2 : (seg == 2) ? d3 : d4;
    }
    float4 v = ((const float4*)s)[off];
    ushort4 o = { f2b(v.x), f2b(v.y), f2b(v.z), f2b(v.w) };
    ((ushort4*)d)[off] = o;
  }
}

// -------- past_k: fp32 copy to out k-region rows 0..2047 + bf16 to kb --------
__global__ void k_past_k(const float* __restrict__ pk, float* __restrict__ outk,
                         u16* __restrict__ kb, int n4){
  int i = blockIdx.x * blockDim.x + threadIdx.x;
  int stride = gridDim.x * blockDim.x;
  for (; i < n4; i += stride){
    int g = i * 4;
    int c = g & 127;
    int r = g >> 7;
    int bh = r >> 11;
    int s = r & 2047;
    long dst = ((long)bh * FULLS + s) * HD + c;
    float4 v = ((const float4*)pk)[i];
    *(float4*)(outk + dst) = v;
    ushort4 o = { f2b(v.x), f2b(v.y), f2b(v.z), f2b(v.w) };
    *(ushort4*)(kb + dst) = o;
  }
}

// -------- past_v: fp32 copy + bf16 TRANSPOSED into vtb[bh][d][key] --------
__global__ void k_past_v(const float* __restrict__ pv, float* __restrict__ outv,
                         u16* __restrict__ vtb){
  __shared__ float tile[32][33];
  int bh = blockIdx.z;
  int d0 = blockIdx.x * 32;
  int s0 = blockIdx.y * 32;
  int tx = threadIdx.x, ty = threadIdx.y;
  const float* src = pv + (long)bh * PASTN * HD;
  float* dstv = outv + (long)bh * FULLS * HD;
#pragma unroll
  for (int k = 0; k < 4; k++){
    int si = ty + 8 * k;
    float v = src[(long)(s0 + si) * HD + d0 + tx];
    dstv[(long)(s0 + si) * HD + d0 + tx] = v;
    tile[si][tx] = v;
  }
  __syncthreads();
  u16* dstt = vtb + (long)bh * HD * FULLS;
#pragma unroll
  for (int k = 0; k < 4; k++){
    int di = ty + 8 * k;
    dstt[(long)(d0 + di) * FULLS + (s0 + tx)] = f2b(tile[tx][di]);
  }
}

// ---- fused QKV bt-GEMM: C = x(4096x2048) * W^T for W in {Wq,Wk,Wv} ----
// grid (48, 32): blockIdx.x selects W by n0>>11 (tiles never straddle).
// Epilogues: q->qb bf16; k->kb bf16 + outk fp32; v->vtb bf16^T + outv fp32.
__global__ void k_gemm_qkv(const u16* __restrict__ A,
                           const u16* __restrict__ Bq, const u16* __restrict__ Bk,
                           const u16* __restrict__ Bv,
                           u16* __restrict__ qb, u16* __restrict__ kbb,
                           u16* __restrict__ vtb,
                           float* __restrict__ outk, float* __restrict__ outv)
{
  __shared__ u16 As[128 * 64];
  __shared__ u16 Bs[128 * 64];
  const int K = DM;
  const int tid = threadIdx.x;
  const int w = tid >> 6, l = tid & 63;
  const int m0 = blockIdx.y * 128, n0 = blockIdx.x * 128;
  const int which = n0 >> 11;
  const u16* Bm = (which == 0) ? Bq : (which == 1) ? Bk : Bv;
  const int nbase = n0 & 2047;
  const int wr = w >> 1, wc = w & 1;
  const int lr = l & 15;
  const int lkb = (l >> 4) * 16;
  f32x4 acc[4][4] = {};

  for (int kt = 0; kt < K; kt += 64){
#pragma unroll
    for (int it = 0; it < 4; it++){
      int Pw = it * 4096 + w * 1024;
      int P = Pw + l * 16;
      int row = P >> 7, cb = P & 127;
      const u16* ga = A + (long)(m0 + row) * K + kt + (cb >> 1);
      __builtin_amdgcn_global_load_lds((gp_t)(const void*)ga, (lp_t)(void*)((char*)As + Pw), 16, 0, 0);
      const u16* gb = Bm + (long)(nbase + row) * K + kt + (cb >> 1);
      __builtin_amdgcn_global_load_lds((gp_t)(const void*)gb, (lp_t)(void*)((char*)Bs + Pw), 16, 0, 0);
    }
    __syncthreads();
#pragma unroll
    for (int kk = 0; kk < 2; kk++){
      bf16x8 af[4], bf[4];
#pragma unroll
      for (int i = 0; i < 4; i++){
        af[i] = *(const bf16x8*)((const char*)As + (wr * 64 + i * 16 + lr) * 128 + kk * 64 + lkb);
        bf[i] = *(const bf16x8*)((const char*)Bs + (wc * 64 + i * 16 + lr) * 128 + kk * 64 + lkb);
      }
#pragma unroll
      for (int i = 0; i < 4; i++)
#pragma unroll
        for (int j = 0; j < 4; j++)
          acc[i][j] = __builtin_amdgcn_mfma_f32_16x16x32_bf16(af[i], bf[j], acc[i][j], 0, 0, 0);
    }
    __syncthreads();
  }

  const int rbase = m0 + wr * 64 + ((l >> 4) << 2);
  const int cbase = wc * 64 + lr;            // within the 2048-wide W slice
#pragma unroll
  for (int i = 0; i < 4; i++){
#pragma unroll
    for (int j = 0; j < 4; j++){
      const int nl = (nbase + cbase + j * 16);
      const int h = nl >> 7, dd = nl & 127;
      if (which == 2){
        const int mm = rbase + i * 16;
        const int b = mm >> 11, s = mm & 2047;
        const int bh = b * NH + h;
        ushort4 pk = { f2b(acc[i][j][0]), f2b(acc[i][j][1]), f2b(acc[i][j][2]), f2b(acc[i][j][3]) };
        *(ushort4*)(vtb + ((long)bh * HD + dd) * FULLS + PASTN + s) = pk;
#pragma unroll
        for (int r = 0; r < 4; r++){
          long idx = ((long)bh * FULLS + PASTN + s + r) * HD + dd;
          outv[idx] = acc[i][j][r];
        }
      } else if (which == 1){
#pragma unroll
        for (int r = 0; r < 4; r++){
          const int mm = rbase + i * 16 + r;
          const int b = mm >> 11, s = mm & 2047;
          long idx = (((long)(b * NH + h)) * FULLS + PASTN + s) * HD + dd;
          float v = acc[i][j][r];
          kbb[idx] = f2b(v);
          outk[idx] = v;
        }
      } else {
#pragma unroll
        for (int r = 0; r < 4; r++){
          const int mm = rbase + i * 16 + r;
          const int b = mm >> 11, s = mm & 2047;
          qb[(((long)(b * NH + h)) * SEQ + s) * HD + dd] = f2b(acc[i][j][r]);
        }
      }
    }
  }
}

// ---------------- O-projection bt-GEMM (fp32 out, row-major) ----------------
__global__ void k_gemm_o(const u16* __restrict__ A, const u16* __restrict__ Bm,
                         float* __restrict__ outf, int M, int N, int K)
{
  __shared__ u16 As[128 * 64];
  __shared__ u16 Bs[128 * 64];
  const int tid = threadIdx.x;
  const int w = tid >> 6, l = tid & 63;
  const int m0 = blockIdx.y * 128, n0 = blockIdx.x * 128;
  const int wr = w >> 1, wc = w & 1;
  const int lr = l & 15;
  const int lkb = (l >> 4) * 16;
  f32x4 acc[4][4] = {};

  for (int kt = 0; kt < K; kt += 64){
#pragma unroll
    for (int it = 0; it < 4; it++){
      int Pw = it * 4096 + w * 1024;
      int P = Pw + l * 16;
      int row = P >> 7, cb = P & 127;
      const u16* ga = A + (long)(m0 + row) * K + kt + (cb >> 1);
      __builtin_amdgcn_global_load_lds((gp_t)(const void*)ga, (lp_t)(void*)((char*)As + Pw), 16, 0, 0);
      const u16* gb = Bm + (long)(n0 + row) * K + kt + (cb >> 1);
      __builtin_amdgcn_global_load_lds((gp_t)(const void*)gb, (lp_t)(void*)((char*)Bs + Pw), 16, 0, 0);
    }
    __syncthreads();
#pragma unroll
    for (int kk = 0; kk < 2; kk++){
      bf16x8 af[4], bf[4];
#pragma unroll
      for (int i = 0; i < 4; i++){
        af[i] = *(const bf16x8*)((const char*)As + (wr * 64 + i * 16 + lr) * 128 + kk * 64 + lkb);
        bf[i] = *(const bf16x8*)((const char*)Bs + (wc * 64 + i * 16 + lr) * 128 + kk * 64 + lkb);
      }
#pragma unroll
      for (int i = 0; i < 4; i++)
#pragma unroll
        for (int j = 0; j < 4; j++)
          acc[i][j] = __builtin_amdgcn_mfma_f32_16x16x32_bf16(af[i], bf[j], acc[i][j], 0, 0, 0);
    }
    __syncthreads();
  }

  const int rbase = m0 + wr * 64 + ((l >> 4) << 2);
  const int cbase = n0 + wc * 64 + lr;
#pragma unroll
  for (int i = 0; i < 4; i++)
#pragma unroll
    for (int j = 0; j < 4; j++){
      const int nn = cbase + j * 16;
#pragma unroll
      for (int r = 0; r < 4; r++)
        outf[(long)(rbase + i * 16 + r) * N + nn] = acc[i][j][r];
    }
}

// ------- flash attention: 4 waves x 32 q-rows, 32x32x16 MFMA, swapped QK^T,
// ------- in-register softmax, T15 2-state pipeline, precomputed LDS addrs,
// ------- permlane32_swap pack/reduce, XCD-chunked tail-balanced block map.
__global__ __launch_bounds__(256, 2)
void k_attn(const u16* __restrict__ qb, const u16* __restrict__ kb,
            const u16* __restrict__ vtb, u16* __restrict__ ab)
{
  __shared__ u16 Ks[2][64 * 128];    // [key][d] 256B rows, 16-slot swizzle
  __shared__ u16 Vs[2][128 * 64];    // [d][key] 128B rows, 8-slot swizzle
  const int tid = threadIdx.x, w = tid >> 6, l = tid & 63;
  const int lq = l & 31, hi = l >> 5;
  const int dd0 = blockIdx.x;
  const int xcd = dd0 & 7;
  const int j   = dd0 >> 3;
  const int ja = j >> 5, jb = (j >> 1) & 15, jc = j & 1;
  const int bh  = xcd * 4 + 2 * ja + jc;
  const int q0b = ((ja ^ jc) ? (15 - jb) : jb) << 7;
  const int qbase = q0b + w * 32;
  const int qpos = PASTN + qbase + lq;
  const u16* qhead = qb + (long)bh * SEQ * HD;
  const u16* khead = kb + (long)bh * FULLS * HD;
  const u16* vhead = vtb + (long)bh * HD * FULLS;

  const float qscale = 0.08838834764831845f * 1.4426950408889634f;
  bf16x8 qf[8];
#pragma unroll
  for (int ks = 0; ks < 8; ks++){
    bf16x8 tq = *(const bf16x8*)(qhead + (long)(qbase + lq) * HD + ks * 16 + hi * 8);
#pragma unroll
    for (int jj = 0; jj < 8; jj++) tq[jj] = (short)f2b(b2f((u16)tq[jj]) * qscale);
    qf[ks] = tq;
  }

  const int kswz = (lq & 15) << 4;
  const int vswz = (lq & 7) << 4;
  const char* kaddr[8];
#pragma unroll
  for (int ks = 0; ks < 8; ks++)
    kaddr[ks] = (const char*)Ks + lq * 256 + ((ks * 32 + hi * 16) ^ kswz);
  const char* vaddr[4];
#pragma unroll
  for (int ks2 = 0; ks2 < 4; ks2++)
    vaddr[ks2] = (const char*)Vs + lq * 128 + ((ks2 * 32 + hi * 16) ^ vswz);

  int ksrcoff[4], vsrcoff[4];
#pragma unroll
  for (int it = 0; it < 4; it++){
    int P = it * 4096 + w * 1024 + l * 16;
    ksrcoff[it] = P ^ (((P >> 8) & 15) << 4);
    int row = P >> 7;
    int cb = (P & 127) ^ ((row & 7) << 4);
    vsrcoff[it] = row * 8192 + cb;
  }

  auto stageK = [&](int t, int bufo){
    const char* src = (const char*)khead + ((long)t << 14);
    char* dstb = (char*)Ks + bufo + w * 1024;
#pragma unroll
    for (int it = 0; it < 4; it++)
      __builtin_amdgcn_global_load_lds((gp_t)(const void*)(src + ksrcoff[it]),
                                       (lp_t)(void*)(dstb + it * 4096), 16, 0, 0);
  };
  auto stageV = [&](int t, int bufo){
    const char* src = (const char*)vhead + ((long)t << 7);
    char* dstb = (char*)Vs + bufo + w * 1024;
#pragma unroll
    for (int it = 0; it < 4; it++)
      __builtin_amdgcn_global_load_lds((gp_t)(const void*)(src + vsrcoff[it]),
                                       (lp_t)(void*)(dstb + it * 4096), 16, 0, 0);
  };

  f32x16 acc[4] = {};
  float m_run = -1e30f, l_run = 0.f;
  const int ntiles = (PASTN + q0b + 128) >> 6;   // always even

  auto finishPV = [&](f32x16& sp0, f32x16& sp1, int vbufo){
    float a0[8];
#pragma unroll
    for (int i = 0; i < 8; i++)
      a0[i] = fmaxf(fmaxf(sp0[i], sp0[i + 8]), fmaxf(sp1[i], sp1[i + 8]));
    float mx = fmaxf(fmaxf(fmaxf(a0[0], a0[1]), fmaxf(a0[2], a0[3])),
                     fmaxf(fmaxf(a0[4], a0[5]), fmaxf(a0[6], a0[7])));
    { float xa = mx, xb = mx;
      asm("v_permlane32_swap_b32 %0, %1" : "+v"(xa), "+v"(xb));
      mx = fmaxf(xa, xb); }

    if (!__all(mx <= m_run + 8.f)){
      float mnew = fmaxf(m_run, mx);
      float corr = __builtin_exp2f(m_run - mnew);
      m_run = mnew; l_run *= corr;
#pragma unroll
      for (int r = 0; r < 16; r++){
        int qlr = (r & 3) + 8 * (r >> 2) + 4 * hi;
        float cr = __shfl(corr, qlr);
#pragma unroll
        for (int d2 = 0; d2 < 4; d2++) acc[d2][r] *= cr;
      }
    }

    float rs = 0.f;
#pragma unroll
    for (int r = 0; r < 16; r++){
      sp0[r] = __builtin_exp2f(sp0[r] - m_run); rs += sp0[r];
      sp1[r] = __builtin_exp2f(sp1[r] - m_run); rs += sp1[r];
    }
    { float ra = rs, rb = rs;
      asm("v_permlane32_swap_b32 %0, %1" : "+v"(ra), "+v"(rb));
      l_run += ra + rb; }

    bf16x8 pfrag[4];
#pragma unroll
    for (int kb2 = 0; kb2 < 2; kb2++){
      const f32x16& sp = kb2 ? sp1 : sp0;
#pragma unroll
      for (int half = 0; half < 2; half++){
        const int h8 = half * 8;
        u32 A0 = cvtpk(sp[h8 + 0], sp[h8 + 1]);
        u32 A1 = cvtpk(sp[h8 + 2], sp[h8 + 3]);
        u32 B0 = cvtpk(sp[h8 + 4], sp[h8 + 5]);
        u32 B1 = cvtpk(sp[h8 + 6], sp[h8 + 7]);
        asm("v_permlane32_swap_b32 %0, %1" : "+v"(A0), "+v"(B0));
        asm("v_permlane32_swap_b32 %0, %1" : "+v"(A1), "+v"(B1));
        union { u32 wd[4]; bf16x8 v; } F;
        F.wd[0] = A0; F.wd[1] = A1; F.wd[2] = B0; F.wd[3] = B1;
        pfrag[kb2 * 2 + half] = F.v;
      }
    }

    __builtin_amdgcn_s_setprio(1);
#pragma unroll
    for (int ks2 = 0; ks2 < 4; ks2++)
#pragma unroll
      for (int d2 = 0; d2 < 4; d2++){
        bf16x8 vf = *(const bf16x8*)(vaddr[ks2] + vbufo + d2 * 4096);
        acc[d2] = __builtin_amdgcn_mfma_f32_32x32x16_bf16(pfrag[ks2], vf, acc[d2], 0, 0, 0);
      }
    __builtin_amdgcn_s_setprio(0);
  };

#define QKT_MASK(T_, BUFC_, SC0_, SC1_)                                        \
  {                                                                            \
    SC0_ = zero16(); SC1_ = zero16();                                          \
    __builtin_amdgcn_s_setprio(1);                                             \
    _Pragma("unroll")                                                          \
    for (int ks = 0; ks < 8; ks++){                                            \
      bf16x8 kf0 = *(const bf16x8*)(kaddr[ks] + (BUFC_));                      \
      bf16x8 kf1 = *(const bf16x8*)(kaddr[ks] + (BUFC_) + 8192);               \
      SC0_ = __builtin_amdgcn_mfma_f32_32x32x16_bf16(kf0, qf[ks], SC0_, 0,0,0);\
      SC1_ = __builtin_amdgcn_mfma_f32_32x32x16_bf16(kf1, qf[ks], SC1_, 0,0,0);\
    }                                                                          \
    __builtin_amdgcn_s_setprio(0);                                             \
    const int kvb_ = (T_) * 64;                                                \
    if (kvb_ + 63 > PASTN + qbase){                                            \
      _Pragma("unroll")                                                        \
      for (int r = 0; r < 16; r++){                                            \
        int key = kvb_ + (r & 3) + 8 * (r >> 2) + 4 * hi;                      \
        if (key > qpos) SC0_[r] = -1e30f;                                      \
        if (key + 32 > qpos) SC1_[r] = -1e30f;                                 \
      }                                                                        \
    }                                                                          \
  }

#define STEP(T_, BUFC_, SP0_, SP1_, SC0_, SC1_)                                \
  {                                                                            \
    if ((T_) + 1 < ntiles) stageK((T_) + 1, (BUFC_) ^ 16384);                  \
    QKT_MASK(T_, BUFC_, SC0_, SC1_);                                           \
    finishPV(SP0_, SP1_, (BUFC_) ^ 16384);                                     \
    __syncthreads();                                                           \
    if ((T_) + 1 < ntiles) stageV((T_) + 1, (BUFC_) ^ 16384);                  \
  }

  f32x16 PA0, PA1, PB0, PB1;

  stageK(0, 0); stageV(0, 0);
  __syncthreads();

  stageK(1, 16384);
  QKT_MASK(0, 0, PA0, PA1);
  __syncthreads();
  stageV(1, 16384);

  for (int t = 1; t + 2 < ntiles; t += 2){
    STEP(t,     16384, PA0, PA1, PB0, PB1);
    STEP(t + 1, 0,     PB0, PB1, PA0, PA1);
  }
  STEP(ntiles - 1, 16384, PA0, PA1, PB0, PB1);
  finishPV(PB0, PB1, 16384);

#undef STEP
#undef QKT_MASK

  float inv = 1.0f / l_run;
  const int b = bh >> 4, h = bh & 15;
#pragma unroll
  for (int r = 0; r < 16; r++){
    int qlr = (r & 3) + 8 * (r >> 2) + 4 * hi;
    float ir = __shfl(inv, qlr);
    long rowbase = ((long)b * SEQ + (qbase + qlr)) * DM + h * HD;
#pragma unroll
    for (int d2 = 0; d2 < 4; d2++)
      ab[rowbase + d2 * 32 + lq] = f2b(acc[d2][r] * ir);
  }
}

extern "C" void kernel_launch(void* const* d_in, const int* in_sizes, int n_in,
                              void* d_out, int out_size, void* d_ws, size_t ws_size,
                              hipStream_t stream) {
  const float* x      = (const float*)d_in[0];
  const float* past_k = (const float*)d_in[1];
  const float* past_v = (const float*)d_in[2];
  const float* Wq     = (const float*)d_in[3];
  const float* Wk     = (const float*)d_in[4];
  const float* Wv     = (const float*)d_in[5];
  const float* Wo     = (const float*)d_in[6];

  float* out  = (float*)d_out;
  float* outk = out + 8388608;       // B*S*DM
  float* outv = out + 25165824;      // + B*NH*FULLS*HD

  char* ws = (char*)d_ws;
  u16* wqb = (u16*)ws;
  u16* wkb = (u16*)(ws + 8388608);
  u16* wvb = (u16*)(ws + 16777216);
  u16* wob = (u16*)(ws + 25165824);
  u16* xb  = (u16*)(ws + 33554432);
  u16* qb  = (u16*)(ws + 50331648);
  u16* kb  = (u16*)(ws + 67108864);
  u16* vtb = (u16*)(ws + 100663296);
  u16* ab  = xb;                     // alias: x consumed before attn writes

  k_conv5<<<2048, 256, 0, stream>>>(x, Wq, Wk, Wv, Wo, xb, wqb, wkb, wvb, wob);
  k_past_k<<<2048, 256, 0, stream>>>(past_k, outk, kb, 2097152);
  k_past_v<<<dim3(4, 64, 32), dim3(32, 8), 0, stream>>>(past_v, outv, vtb);

  k_gemm_qkv<<<dim3(48, 32), 256, 0, stream>>>(xb, wqb, wkb, wvb,
                                               qb, kb, vtb, outk, outv);

  k_attn<<<512, 256, 0, stream>>>(qb, kb, vtb, ab);

  k_gemm_o<<<dim3(16, 32), 256, 0, stream>>>(ab, wob, out, 4096, 2048, 2048);
}

// Round 8
// 402.105 us; speedup vs baseline: 1.2648x; 1.0370x over previous
//
#include <hip/hip_runtime.h>
#include <hip/hip_bf16.h>
#include <stdint.h>

typedef __attribute__((ext_vector_type(8))) short bf16x8;
typedef __attribute__((ext_vector_type(4))) float f32x4;
typedef __attribute__((ext_vector_type(16))) float f32x16;
typedef unsigned short u16;
typedef unsigned int u32;
typedef const __attribute__((address_space(1))) u32* gp_t;
typedef __attribute__((address_space(3))) u32* lp_t;

#define HD 128
#define NH 16
#define SEQ 2048
#define PASTN 2048
#define FULLS 4096
#define DM 2048

__device__ __forceinline__ u16 f2b(float f){
  union { float f; u32 u; } v; v.f = f;
  return (u16)((v.u + 0x7fffu + ((v.u >> 16) & 1u)) >> 16);
}
__device__ __forceinline__ float b2f(u16 b){
  union { u32 u; float f; } v; v.u = ((u32)b) << 16;
  return v.f;
}
__device__ __forceinline__ u32 cvtpk(float lo, float hi){
  u32 r; asm("v_cvt_pk_bf16_f32 %0, %1, %2" : "=v"(r) : "v"(lo), "v"(hi)); return r;
}
__device__ __forceinline__ f32x16 zero16(){ f32x16 z = {}; return z; }

// ------- fused fp32->bf16 convert of x, Wq, Wk, Wv, Wo (one launch) -------
__global__ void k_conv5(const float* __restrict__ sx,
                        const float* __restrict__ s1, const float* __restrict__ s2,
                        const float* __restrict__ s3, const float* __restrict__ s4,
                        u16* __restrict__ dx,
                        u16* __restrict__ d1, u16* __restrict__ d2,
                        u16* __restrict__ d3, u16* __restrict__ d4)
{
  const int total = 2097152 + 4 * 1048576;
  int i = blockIdx.x * blockDim.x + threadIdx.x;
  int stride = gridDim.x * blockDim.x;
  for (; i < total; i += stride){
    const float* s; u16* d; int off;
    if (i < 2097152){ s = sx; d = dx; off = i; }
    else {
      int t = i - 2097152;
      int seg = t >> 20; off = t & 1048575;
      s = (seg == 0) ? s1 : (seg == 1) ? s2 : (seg == 2) ? s3 : s4;
      d = (seg == 0) ? d1 : (seg == 1) ? d2 : (seg == 2) ? d3 : d4;
    }
    float4 v = ((const float4*)s)[off];
    ushort4 o = { f2b(v.x), f2b(v.y), f2b(v.z), f2b(v.w) };
    ((ushort4*)d)[off] = o;
  }
}

// -------- past_k: fp32 copy to out k-region rows 0..2047 + bf16 to kb --------
__global__ void k_past_k(const float* __restrict__ pk, float* __restrict__ outk,
                         u16* __restrict__ kb, int n4){
  int i = blockIdx.x * blockDim.x + threadIdx.x;
  int stride = gridDim.x * blockDim.x;
  for (; i < n4; i += stride){
    int g = i * 4;
    int c = g & 127;
    int r = g >> 7;
    int bh = r >> 11;
    int s = r & 2047;
    long dst = ((long)bh * FULLS + s) * HD + c;
    float4 v = ((const float4*)pk)[i];
    *(float4*)(outk + dst) = v;
    ushort4 o = { f2b(v.x), f2b(v.y), f2b(v.z), f2b(v.w) };
    *(ushort4*)(kb + dst) = o;
  }
}

// -------- past_v: fp32 copy + bf16 TRANSPOSED into vtb[bh][d][key] --------
__global__ void k_past_v(const float* __restrict__ pv, float* __restrict__ outv,
                         u16* __restrict__ vtb){
  __shared__ float tile[32][33];
  int bh = blockIdx.z;
  int d0 = blockIdx.x * 32;
  int s0 = blockIdx.y * 32;
  int tx = threadIdx.x, ty = threadIdx.y;
  const float* src = pv + (long)bh * PASTN * HD;
  float* dstv = outv + (long)bh * FULLS * HD;
#pragma unroll
  for (int k = 0; k < 4; k++){
    int si = ty + 8 * k;
    float v = src[(long)(s0 + si) * HD + d0 + tx];
    dstv[(long)(s0 + si) * HD + d0 + tx] = v;
    tile[si][tx] = v;
  }
  __syncthreads();
  u16* dstt = vtb + (long)bh * HD * FULLS;
#pragma unroll
  for (int k = 0; k < 4; k++){
    int di = ty + 8 * k;
    dstt[(long)(d0 + di) * FULLS + (s0 + tx)] = f2b(tile[tx][di]);
  }
}

// ==== fused QKV bt-GEMM, 256^2 8-phase template (m201-style) ====
// 512 thr = 8 waves (2M x 4N), BM=BN=256, BK=64, per-wave out 128x64.
// LDS 128KB: A[2par][2half][128][64] @0, B same @65536. T2 swizzle
// byte^=((row&7)<<4), inverse-swizzled global source (rule 21).
// Stage ring per iter (tiles c0=2i,c1=2i+1): ph1,2: c1.A; ph3,4: (c0+2).B;
// ph5,6: (c0+2).A; ph7,8: (c1+2).B. vmcnt(4) only at ph4/ph8 ends.
__global__ __launch_bounds__(512, 1)
void k_gemm_qkv8(const u16* __restrict__ A,
                 const u16* __restrict__ Bq, const u16* __restrict__ Bk,
                 const u16* __restrict__ Bv,
                 u16* __restrict__ qb, u16* __restrict__ kbb,
                 u16* __restrict__ vtb,
                 float* __restrict__ outk, float* __restrict__ outv)
{
  __shared__ char LDS[131072];
  const int tid = threadIdx.x, w = tid >> 6, l = tid & 63;
  const int wm = w >> 2, wn = w & 3;
  const int m0 = blockIdx.y * 256;
  const int which = blockIdx.x >> 3;
  const u16* Bm = (which == 0) ? Bq : (which == 1) ? Bk : Bv;
  const int n0s = (blockIdx.x & 7) * 256;   // slice-local N base

  // ds_read lane constants (reader-side swizzle; row&7 == l&7 everywhere)
  const int aoff0 = (((l >> 4) * 16) ^ ((l & 7) << 4));
  const int aoff1 = ((64 + (l >> 4) * 16) ^ ((l & 7) << 4));
  const char* ArdB = LDS + wm * 16384 + (l & 15) * 128;
  const char* BrdB = LDS + 65536 + (wn >> 1) * 16384 + (wn & 1) * 8192 + (l & 15) * 128;

  // stage lane constants (linear LDS dest, inverse-swizzled global source)
  const int Pa = tid * 16, Pb = tid * 16 + 8192;
  const int ra = Pa >> 7, rb = Pb >> 7;
  const int sro1 = ra * 2048 + ((((Pa & 127) ^ ((ra & 7) << 4))) >> 1);
  const int sro2 = rb * 2048 + ((((Pb & 127) ^ ((rb & 7) << 4))) >> 1);
  char* sd1 = LDS + w * 1024;
  char* sd2 = LDS + w * 1024 + 8192;

  f32x4 acc[8][4] = {};

#define GLDS(SRC, DST) __builtin_amdgcn_global_load_lds((gp_t)(const void*)(SRC), (lp_t)(void*)(DST), 16, 0, 0)
#define STG(MAT, ROWB, C, REG) { const u16* s_ = (MAT) + (long)(ROWB) * 2048 + (C) * 64; \
    GLDS(s_ + sro1, sd1 + (REG)); GLDS(s_ + sro2, sd2 + (REG)); }
#define RDB(DST, PAR) { _Pragma("unroll") for (int nf = 0; nf < 4; nf++){ \
      DST[nf*2]   = *(const bf16x8*)(BrdB + (PAR)*32768 + nf*2048 + aoff0); \
      DST[nf*2+1] = *(const bf16x8*)(BrdB + (PAR)*32768 + nf*2048 + aoff1); } }
#define RDA(PAR, MF) \
      a0 = *(const bf16x8*)(ArdB + (PAR)*32768 + (MF)*2048 + aoff0); \
      a1 = *(const bf16x8*)(ArdB + (PAR)*32768 + (MF)*2048 + aoff1); \
      a2 = *(const bf16x8*)(ArdB + (PAR)*32768 + (MF+1)*2048 + aoff0); \
      a3 = *(const bf16x8*)(ArdB + (PAR)*32768 + (MF+1)*2048 + aoff1);
#define BARW { __builtin_amdgcn_s_barrier(); \
      asm volatile("s_waitcnt lgkmcnt(0)" ::: "memory"); \
      __builtin_amdgcn_sched_barrier(0); }
#define MM(BF, MF) { __builtin_amdgcn_s_setprio(1); \
      _Pragma("unroll") for (int nf = 0; nf < 4; nf++){ \
        acc[MF][nf]   = __builtin_amdgcn_mfma_f32_16x16x32_bf16(a0, BF[nf*2],   acc[MF][nf],   0,0,0); \
        acc[MF][nf]   = __builtin_amdgcn_mfma_f32_16x16x32_bf16(a1, BF[nf*2+1], acc[MF][nf],   0,0,0); \
        acc[MF+1][nf] = __builtin_amdgcn_mfma_f32_16x16x32_bf16(a2, BF[nf*2],   acc[MF+1][nf], 0,0,0); \
        acc[MF+1][nf] = __builtin_amdgcn_mfma_f32_16x16x32_bf16(a3, BF[nf*2+1], acc[MF+1][nf], 0,0,0); } \
      __builtin_amdgcn_s_setprio(0); }

  // ---- prologue: tile0 full + tile1 B (order matters for vmcnt(4)) ----
  STG(A,  m0,        0, 0);
  STG(A,  m0 + 128,  0, 16384);
  STG(Bm, n0s,       0, 65536);
  STG(Bm, n0s + 128, 0, 81920);
  STG(Bm, n0s,       1, 98304);
  STG(Bm, n0s + 128, 1, 114688);
  asm volatile("s_waitcnt vmcnt(4)" ::: "memory");
  __builtin_amdgcn_s_barrier();

  for (int i = 0; i < 16; ++i){
    const int c1 = 2 * i + 1;
    const int cn = 2 * i + 2;
    const bool nlast = (i < 15);
    bf16x8 b0[8], b1[8];
    bf16x8 a0, a1, a2, a3;

    // ph1
    RDB(b0, 0); RDA(0, 0);
    STG(A, m0, c1, 32768);
    BARW; MM(b0, 0);
    __builtin_amdgcn_s_barrier();
    // ph2
    RDA(0, 2);
    STG(A, m0 + 128, c1, 49152);
    BARW; MM(b0, 2);
    __builtin_amdgcn_s_barrier();
    // ph3
    RDA(0, 4);
    if (nlast) STG(Bm, n0s, cn, 65536);
    BARW; MM(b0, 4);
    __builtin_amdgcn_s_barrier();
    // ph4
    RDA(0, 6);
    if (nlast) STG(Bm, n0s + 128, cn, 81920);
    BARW; MM(b0, 6);
    if (nlast) { asm volatile("s_waitcnt vmcnt(4)" ::: "memory"); }
    else       { asm volatile("s_waitcnt vmcnt(0)" ::: "memory"); }
    __builtin_amdgcn_s_barrier();
    // ph5
    RDB(b1, 1); RDA(1, 0);
    if (nlast) STG(A, m0, cn, 0);
    BARW; MM(b1, 0);
    __builtin_amdgcn_s_barrier();
    // ph6
    RDA(1, 2);
    if (nlast) STG(A, m0 + 128, cn, 16384);
    BARW; MM(b1, 2);
    __builtin_amdgcn_s_barrier();
    // ph7
    RDA(1, 4);
    if (nlast) STG(Bm, n0s, cn + 1, 98304);
    BARW; MM(b1, 4);
    __builtin_amdgcn_s_barrier();
    // ph8
    RDA(1, 6);
    if (nlast) STG(Bm, n0s + 128, cn + 1, 114688);
    BARW; MM(b1, 6);
    if (nlast) { asm volatile("s_waitcnt vmcnt(4)" ::: "memory"); }
    __builtin_amdgcn_s_barrier();
  }

#undef MM
#undef BARW
#undef RDA
#undef RDB
#undef STG
#undef GLDS

  // ---- epilogue ----
  const int rbase = m0 + wm * 128 + ((l >> 4) << 2);
  const int cb2 = n0s + wn * 64 + (l & 15);
#pragma unroll
  for (int mf = 0; mf < 8; mf++){
#pragma unroll
    for (int nf = 0; nf < 4; nf++){
      const int nl = cb2 + nf * 16;
      const int h = nl >> 7, dd = nl & 127;
      if (which == 2){
        const int mm = rbase + mf * 16;
        const int b = mm >> 11, s = mm & 2047;
        const int bh = b * NH + h;
        ushort4 pk = { f2b(acc[mf][nf][0]), f2b(acc[mf][nf][1]), f2b(acc[mf][nf][2]), f2b(acc[mf][nf][3]) };
        *(ushort4*)(vtb + ((long)bh * HD + dd) * FULLS + PASTN + s) = pk;
#pragma unroll
        for (int r = 0; r < 4; r++){
          long idx = ((long)bh * FULLS + PASTN + s + r) * HD + dd;
          outv[idx] = acc[mf][nf][r];
        }
      } else if (which == 1){
#pragma unroll
        for (int r = 0; r < 4; r++){
          const int mm = rbase + mf * 16 + r;
          const int b = mm >> 11, s = mm & 2047;
          long idx = (((long)(b * NH + h)) * FULLS + PASTN + s) * HD + dd;
          float v = acc[mf][nf][r];
          kbb[idx] = f2b(v);
          outk[idx] = v;
        }
      } else {
#pragma unroll
        for (int r = 0; r < 4; r++){
          const int mm = rbase + mf * 16 + r;
          const int b = mm >> 11, s = mm & 2047;
          qb[(((long)(b * NH + h)) * SEQ + s) * HD + dd] = f2b(acc[mf][nf][r]);
        }
      }
    }
  }
}

// ---------------- O-projection bt-GEMM (fp32 out, row-major) ----------------
__global__ void k_gemm_o(const u16* __restrict__ A, const u16* __restrict__ Bm,
                         float* __restrict__ outf, int M, int N, int K)
{
  __shared__ u16 As[128 * 64];
  __shared__ u16 Bs[128 * 64];
  const int tid = threadIdx.x;
  const int w = tid >> 6, l = tid & 63;
  const int m0 = blockIdx.y * 128, n0 = blockIdx.x * 128;
  const int wr = w >> 1, wc = w & 1;
  const int lr = l & 15;
  const int lkb = (l >> 4) * 16;
  f32x4 acc[4][4] = {};

  for (int kt = 0; kt < K; kt += 64){
#pragma unroll
    for (int it = 0; it < 4; it++){
      int Pw = it * 4096 + w * 1024;
      int P = Pw + l * 16;
      int row = P >> 7, cb = P & 127;
      const u16* ga = A + (long)(m0 + row) * K + kt + (cb >> 1);
      __builtin_amdgcn_global_load_lds((gp_t)(const void*)ga, (lp_t)(void*)((char*)As + Pw), 16, 0, 0);
      const u16* gb = Bm + (long)(n0 + row) * K + kt + (cb >> 1);
      __builtin_amdgcn_global_load_lds((gp_t)(const void*)gb, (lp_t)(void*)((char*)Bs + Pw), 16, 0, 0);
    }
    __syncthreads();
#pragma unroll
    for (int kk = 0; kk < 2; kk++){
      bf16x8 af[4], bf[4];
#pragma unroll
      for (int i = 0; i < 4; i++){
        af[i] = *(const bf16x8*)((const char*)As + (wr * 64 + i * 16 + lr) * 128 + kk * 64 + lkb);
        bf[i] = *(const bf16x8*)((const char*)Bs + (wc * 64 + i * 16 + lr) * 128 + kk * 64 + lkb);
      }
#pragma unroll
      for (int i = 0; i < 4; i++)
#pragma unroll
        for (int j = 0; j < 4; j++)
          acc[i][j] = __builtin_amdgcn_mfma_f32_16x16x32_bf16(af[i], bf[j], acc[i][j], 0, 0, 0);
    }
    __syncthreads();
  }

  const int rbase = m0 + wr * 64 + ((l >> 4) << 2);
  const int cbase = n0 + wc * 64 + lr;
#pragma unroll
  for (int i = 0; i < 4; i++)
#pragma unroll
    for (int j = 0; j < 4; j++){
      const int nn = cbase + j * 16;
#pragma unroll
      for (int r = 0; r < 4; r++)
        outf[(long)(rbase + i * 16 + r) * N + nn] = acc[i][j][r];
    }
}

// ------- flash attention (unchanged from round 7) -------
__global__ __launch_bounds__(256, 2)
void k_attn(const u16* __restrict__ qb, const u16* __restrict__ kb,
            const u16* __restrict__ vtb, u16* __restrict__ ab)
{
  __shared__ u16 Ks[2][64 * 128];
  __shared__ u16 Vs[2][128 * 64];
  const int tid = threadIdx.x, w = tid >> 6, l = tid & 63;
  const int lq = l & 31, hi = l >> 5;
  const int dd0 = blockIdx.x;
  const int xcd = dd0 & 7;
  const int j   = dd0 >> 3;
  const int ja = j >> 5, jb = (j >> 1) & 15, jc = j & 1;
  const int bh  = xcd * 4 + 2 * ja + jc;
  const int q0b = ((ja ^ jc) ? (15 - jb) : jb) << 7;
  const int qbase = q0b + w * 32;
  const int qpos = PASTN + qbase + lq;
  const u16* qhead = qb + (long)bh * SEQ * HD;
  const u16* khead = kb + (long)bh * FULLS * HD;
  const u16* vhead = vtb + (long)bh * HD * FULLS;

  const float qscale = 0.08838834764831845f * 1.4426950408889634f;
  bf16x8 qf[8];
#pragma unroll
  for (int ks = 0; ks < 8; ks++){
    bf16x8 tq = *(const bf16x8*)(qhead + (long)(qbase + lq) * HD + ks * 16 + hi * 8);
#pragma unroll
    for (int jj = 0; jj < 8; jj++) tq[jj] = (short)f2b(b2f((u16)tq[jj]) * qscale);
    qf[ks] = tq;
  }

  const int kswz = (lq & 15) << 4;
  const int vswz = (lq & 7) << 4;
  const char* kaddr[8];
#pragma unroll
  for (int ks = 0; ks < 8; ks++)
    kaddr[ks] = (const char*)Ks + lq * 256 + ((ks * 32 + hi * 16) ^ kswz);
  const char* vaddr[4];
#pragma unroll
  for (int ks2 = 0; ks2 < 4; ks2++)
    vaddr[ks2] = (const char*)Vs + lq * 128 + ((ks2 * 32 + hi * 16) ^ vswz);

  int ksrcoff[4], vsrcoff[4];
#pragma unroll
  for (int it = 0; it < 4; it++){
    int P = it * 4096 + w * 1024 + l * 16;
    ksrcoff[it] = P ^ (((P >> 8) & 15) << 4);
    int row = P >> 7;
    int cb = (P & 127) ^ ((row & 7) << 4);
    vsrcoff[it] = row * 8192 + cb;
  }

  auto stageK = [&](int t, int bufo){
    const char* src = (const char*)khead + ((long)t << 14);
    char* dstb = (char*)Ks + bufo + w * 1024;
#pragma unroll
    for (int it = 0; it < 4; it++)
      __builtin_amdgcn_global_load_lds((gp_t)(const void*)(src + ksrcoff[it]),
                                       (lp_t)(void*)(dstb + it * 4096), 16, 0, 0);
  };
  auto stageV = [&](int t, int bufo){
    const char* src = (const char*)vhead + ((long)t << 7);
    char* dstb = (char*)Vs + bufo + w * 1024;
#pragma unroll
    for (int it = 0; it < 4; it++)
      __builtin_amdgcn_global_load_lds((gp_t)(const void*)(src + vsrcoff[it]),
                                       (lp_t)(void*)(dstb + it * 4096), 16, 0, 0);
  };

  f32x16 acc[4] = {};
  float m_run = -1e30f, l_run = 0.f;
  const int ntiles = (PASTN + q0b + 128) >> 6;

  auto finishPV = [&](f32x16& sp0, f32x16& sp1, int vbufo){
    float a0[8];
#pragma unroll
    for (int i = 0; i < 8; i++)
      a0[i] = fmaxf(fmaxf(sp0[i], sp0[i + 8]), fmaxf(sp1[i], sp1[i + 8]));
    float mx = fmaxf(fmaxf(fmaxf(a0[0], a0[1]), fmaxf(a0[2], a0[3])),
                     fmaxf(fmaxf(a0[4], a0[5]), fmaxf(a0[6], a0[7])));
    { float xa = mx, xb = mx;
      asm("v_permlane32_swap_b32 %0, %1" : "+v"(xa), "+v"(xb));
      mx = fmaxf(xa, xb); }

    if (!__all(mx <= m_run + 8.f)){
      float mnew = fmaxf(m_run, mx);
      float corr = __builtin_exp2f(m_run - mnew);
      m_run = mnew; l_run *= corr;
#pragma unroll
      for (int r = 0; r < 16; r++){
        int qlr = (r & 3) + 8 * (r >> 2) + 4 * hi;
        float cr = __shfl(corr, qlr);
#pragma unroll
        for (int d2 = 0; d2 < 4; d2++) acc[d2][r] *= cr;
      }
    }

    float rs = 0.f;
#pragma unroll
    for (int r = 0; r < 16; r++){
      sp0[r] = __builtin_exp2f(sp0[r] - m_run); rs += sp0[r];
      sp1[r] = __builtin_exp2f(sp1[r] - m_run); rs += sp1[r];
    }
    { float ra = rs, rb = rs;
      asm("v_permlane32_swap_b32 %0, %1" : "+v"(ra), "+v"(rb));
      l_run += ra + rb; }

    bf16x8 pfrag[4];
#pragma unroll
    for (int kb2 = 0; kb2 < 2; kb2++){
      const f32x16& sp = kb2 ? sp1 : sp0;
#pragma unroll
      for (int half = 0; half < 2; half++){
        const int h8 = half * 8;
        u32 A0 = cvtpk(sp[h8 + 0], sp[h8 + 1]);
        u32 A1 = cvtpk(sp[h8 + 2], sp[h8 + 3]);
        u32 B0 = cvtpk(sp[h8 + 4], sp[h8 + 5]);
        u32 B1 = cvtpk(sp[h8 + 6], sp[h8 + 7]);
        asm("v_permlane32_swap_b32 %0, %1" : "+v"(A0), "+v"(B0));
        asm("v_permlane32_swap_b32 %0, %1" : "+v"(A1), "+v"(B1));
        union { u32 wd[4]; bf16x8 v; } F;
        F.wd[0] = A0; F.wd[1] = A1; F.wd[2] = B0; F.wd[3] = B1;
        pfrag[kb2 * 2 + half] = F.v;
      }
    }

    __builtin_amdgcn_s_setprio(1);
#pragma unroll
    for (int ks2 = 0; ks2 < 4; ks2++)
#pragma unroll
      for (int d2 = 0; d2 < 4; d2++){
        bf16x8 vf = *(const bf16x8*)(vaddr[ks2] + vbufo + d2 * 4096);
        acc[d2] = __builtin_amdgcn_mfma_f32_32x32x16_bf16(pfrag[ks2], vf, acc[d2], 0, 0, 0);
      }
    __builtin_amdgcn_s_setprio(0);
  };

#define QKT_MASK(T_, BUFC_, SC0_, SC1_)                                        \
  {                                                                            \
    SC0_ = zero16(); SC1_ = zero16();                                          \
    __builtin_amdgcn_s_setprio(1);                                             \
    _Pragma("unroll")                                                          \
    for (int ks = 0; ks < 8; ks++){                                            \
      bf16x8 kf0 = *(const bf16x8*)(kaddr[ks] + (BUFC_));                      \
      bf16x8 kf1 = *(const bf16x8*)(kaddr[ks] + (BUFC_) + 8192);               \
      SC0_ = __builtin_amdgcn_mfma_f32_32x32x16_bf16(kf0, qf[ks], SC0_, 0,0,0);\
      SC1_ = __builtin_amdgcn_mfma_f32_32x32x16_bf16(kf1, qf[ks], SC1_, 0,0,0);\
    }                                                                          \
    __builtin_amdgcn_s_setprio(0);                                             \
    const int kvb_ = (T_) * 64;                                                \
    if (kvb_ + 63 > PASTN + qbase){                                            \
      _Pragma("unroll")                                                        \
      for (int r = 0; r < 16; r++){                                            \
        int key = kvb_ + (r & 3) + 8 * (r >> 2) + 4 * hi;                      \
        if (key > qpos) SC0_[r] = -1e30f;                                      \
        if (key + 32 > qpos) SC1_[r] = -1e30f;                                 \
      }                                                                        \
    }                                                                          \
  }

#define STEP(T_, BUFC_, SP0_, SP1_, SC0_, SC1_)                                \
  {                                                                            \
    if ((T_) + 1 < ntiles) stageK((T_) + 1, (BUFC_) ^ 16384);                  \
    QKT_MASK(T_, BUFC_, SC0_, SC1_);                                           \
    finishPV(SP0_, SP1_, (BUFC_) ^ 16384);                                     \
    __syncthreads();                                                           \
    if ((T_) + 1 < ntiles) stageV((T_) + 1, (BUFC_) ^ 16384);                  \
  }

  f32x16 PA0, PA1, PB0, PB1;

  stageK(0, 0); stageV(0, 0);
  __syncthreads();

  stageK(1, 16384);
  QKT_MASK(0, 0, PA0, PA1);
  __syncthreads();
  stageV(1, 16384);

  for (int t = 1; t + 2 < ntiles; t += 2){
    STEP(t,     16384, PA0, PA1, PB0, PB1);
    STEP(t + 1, 0,     PB0, PB1, PA0, PA1);
  }
  STEP(ntiles - 1, 16384, PA0, PA1, PB0, PB1);
  finishPV(PB0, PB1, 16384);

#undef STEP
#undef QKT_MASK

  float inv = 1.0f / l_run;
  const int b = bh >> 4, h = bh & 15;
#pragma unroll
  for (int r = 0; r < 16; r++){
    int qlr = (r & 3) + 8 * (r >> 2) + 4 * hi;
    float ir = __shfl(inv, qlr);
    long rowbase = ((long)b * SEQ + (qbase + qlr)) * DM + h * HD;
#pragma unroll
    for (int d2 = 0; d2 < 4; d2++)
      ab[rowbase + d2 * 32 + lq] = f2b(acc[d2][r] * ir);
  }
}

extern "C" void kernel_launch(void* const* d_in, const int* in_sizes, int n_in,
                              void* d_out, int out_size, void* d_ws, size_t ws_size,
                              hipStream_t stream) {
  const float* x      = (const float*)d_in[0];
  const float* past_k = (const float*)d_in[1];
  const float* past_v = (const float*)d_in[2];
  const float* Wq     = (const float*)d_in[3];
  const float* Wk     = (const float*)d_in[4];
  const float* Wv     = (const float*)d_in[5];
  const float* Wo     = (const float*)d_in[6];

  float* out  = (float*)d_out;
  float* outk = out + 8388608;       // B*S*DM
  float* outv = out + 25165824;      // + B*NH*FULLS*HD

  char* ws = (char*)d_ws;
  u16* wqb = (u16*)ws;
  u16* wkb = (u16*)(ws + 8388608);
  u16* wvb = (u16*)(ws + 16777216);
  u16* wob = (u16*)(ws + 25165824);
  u16* xb  = (u16*)(ws + 33554432);
  u16* qb  = (u16*)(ws + 50331648);
  u16* kb  = (u16*)(ws + 67108864);
  u16* vtb = (u16*)(ws + 100663296);
  u16* ab  = xb;                     // alias: x consumed before attn writes

  k_conv5<<<2048, 256, 0, stream>>>(x, Wq, Wk, Wv, Wo, xb, wqb, wkb, wvb, wob);
  k_past_k<<<2048, 256, 0, stream>>>(past_k, outk, kb, 2097152);
  k_past_v<<<dim3(4, 64, 32), dim3(32, 8), 0, stream>>>(past_v, outv, vtb);

  k_gemm_qkv8<<<dim3(24, 16), 512, 0, stream>>>(xb, wqb, wkb, wvb,
                                                qb, kb, vtb, outk, outv);

  k_attn<<<512, 256, 0, stream>>>(qb, kb, vtb, ab);

  k_gemm_o<<<dim3(16, 32), 256, 0, stream>>>(ab, wob, out, 4096, 2048, 2048);
}

// Round 9
// 370.048 us; speedup vs baseline: 1.3744x; 1.0866x over previous
//
#include <hip/hip_runtime.h>
#include <hip/hip_bf16.h>
#include <stdint.h>

typedef __attribute__((ext_vector_type(8))) short bf16x8;
typedef __attribute__((ext_vector_type(4))) float f32x4;
typedef __attribute__((ext_vector_type(16))) float f32x16;
typedef unsigned short u16;
typedef unsigned int u32;
typedef const __attribute__((address_space(1))) u32* gp_t;
typedef __attribute__((address_space(3))) u32* lp_t;

#define HD 128
#define NH 16
#define SEQ 2048
#define PASTN 2048
#define FULLS 4096
#define DM 2048

__device__ __forceinline__ u16 f2b(float f){
  union { float f; u32 u; } v; v.f = f;
  return (u16)((v.u + 0x7fffu + ((v.u >> 16) & 1u)) >> 16);
}
__device__ __forceinline__ float b2f(u16 b){
  union { u32 u; float f; } v; v.u = ((u32)b) << 16;
  return v.f;
}
__device__ __forceinline__ u32 cvtpk(float lo, float hi){
  u32 r; asm("v_cvt_pk_bf16_f32 %0, %1, %2" : "=v"(r) : "v"(lo), "v"(hi)); return r;
}
__device__ __forceinline__ f32x16 zero16(){ f32x16 z = {}; return z; }

// ------- fused fp32->bf16 convert of x, Wq, Wk, Wv, Wo (one launch) -------
__global__ void k_conv5(const float* __restrict__ sx,
                        const float* __restrict__ s1, const float* __restrict__ s2,
                        const float* __restrict__ s3, const float* __restrict__ s4,
                        u16* __restrict__ dx,
                        u16* __restrict__ d1, u16* __restrict__ d2,
                        u16* __restrict__ d3, u16* __restrict__ d4)
{
  const int total = 2097152 + 4 * 1048576;
  int i = blockIdx.x * blockDim.x + threadIdx.x;
  int stride = gridDim.x * blockDim.x;
  for (; i < total; i += stride){
    const float* s; u16* d; int off;
    if (i < 2097152){ s = sx; d = dx; off = i; }
    else {
      int t = i - 2097152;
      int seg = t >> 20; off = t & 1048575;
      s = (seg == 0) ? s1 : (seg == 1) ? s2 : (seg == 2) ? s3 : s4;
      d = (seg == 0) ? d1 : (seg == 1) ? d2 : (seg == 2) ? d3 : d4;
    }
    float4 v = ((const float4*)s)[off];
    ushort4 o = { f2b(v.x), f2b(v.y), f2b(v.z), f2b(v.w) };
    ((ushort4*)d)[off] = o;
  }
}

// ==== fused QKV bt-GEMM (256^2 8-phase) + past-KV copy blocks ====
// grid 512 x 512thr = exactly 2 dispatch waves at 1 block/CU.
// Blocks 0-383: GEMM (which = bx/128, n-tile = (bx%128)>>4, m-tile = bx&15).
// Blocks 384-447: past_k fp32 copy + bf16 convert (fills GEMM tail wave).
// Blocks 448-511: past_v fp32 copy + bf16 transpose into vtb.
__global__ __launch_bounds__(512, 1)
void k_qkv_fused(const u16* __restrict__ A,
                 const u16* __restrict__ Bq, const u16* __restrict__ Bk,
                 const u16* __restrict__ Bv,
                 u16* __restrict__ qb, u16* __restrict__ kbb,
                 u16* __restrict__ vtb,
                 float* __restrict__ outk, float* __restrict__ outv,
                 const float* __restrict__ pk, const float* __restrict__ pv)
{
  __shared__ char LDS[131072];
  const int bx = blockIdx.x;
  const int tid = threadIdx.x;

  if (bx >= 384){
    if (bx < 448){
      // ---- past_k: copy fp32 into outk rows 0..2047 + bf16 into kbb ----
      for (int i = (bx - 384) * 512 + tid; i < 2097152; i += 32768){
        int g = i * 4;
        int c = g & 127;
        int r = g >> 7;
        int bh = r >> 11;
        int s = r & 2047;
        long dst = ((long)bh * FULLS + s) * HD + c;
        float4 v = ((const float4*)pk)[i];
        *(float4*)(outk + dst) = v;
        ushort4 o = { f2b(v.x), f2b(v.y), f2b(v.z), f2b(v.w) };
        *(ushort4*)(kbb + dst) = o;
      }
    } else {
      // ---- past_v: copy fp32 into outv + bf16 TRANSPOSED into vtb ----
      float* ldsF = (float*)LDS;              // [64][129] padded
      for (int cc = 0; cc < 16; cc++){
        int c = ((bx - 448) << 4) + cc;       // 1024 chunks of 64s x 128d
        int bh = c >> 5, s0 = (c & 31) << 6;
        const float* src = pv + ((long)bh * PASTN + s0) * HD;
        float* dsv = outv + ((long)bh * FULLS + s0) * HD;
#pragma unroll
        for (int p = 0; p < 4; p++){
          int idx = tid + p * 512;
          int row = idx >> 5, c4 = (idx & 31) << 2;
          float4 v = *(const float4*)(src + row * HD + c4);
          *(float4*)(dsv + row * HD + c4) = v;
          ldsF[row * 129 + c4 + 0] = v.x;
          ldsF[row * 129 + c4 + 1] = v.y;
          ldsF[row * 129 + c4 + 2] = v.z;
          ldsF[row * 129 + c4 + 3] = v.w;
        }
        __syncthreads();
        int d = tid >> 2, sb = (tid & 3) << 4;
        u16* dst = vtb + ((long)bh * HD + d) * FULLS + s0 + sb;
#pragma unroll
        for (int g = 0; g < 4; g++){
          ushort4 o = { f2b(ldsF[(sb + g * 4 + 0) * 129 + d]),
                        f2b(ldsF[(sb + g * 4 + 1) * 129 + d]),
                        f2b(ldsF[(sb + g * 4 + 2) * 129 + d]),
                        f2b(ldsF[(sb + g * 4 + 3) * 129 + d]) };
          *(ushort4*)(dst + g * 4) = o;
        }
        __syncthreads();
      }
    }
    return;
  }

  // ---------------- GEMM path ----------------
  const int w = tid >> 6, l = tid & 63;
  const int wm = w >> 2, wn = w & 3;
  const int which = bx >> 7;
  const int r0 = bx & 127;
  const int m0 = (r0 & 15) * 256;
  const int n0s = (r0 >> 4) * 256;
  const u16* Bm = (which == 0) ? Bq : (which == 1) ? Bk : Bv;

  const int aoff0 = (((l >> 4) * 16) ^ ((l & 7) << 4));
  const int aoff1 = ((64 + (l >> 4) * 16) ^ ((l & 7) << 4));
  const char* ArdB = LDS + wm * 16384 + (l & 15) * 128;
  const char* BrdB = LDS + 65536 + (wn >> 1) * 16384 + (wn & 1) * 8192 + (l & 15) * 128;

  const int Pa = tid * 16, Pb = tid * 16 + 8192;
  const int ra = Pa >> 7, rb = Pb >> 7;
  const int sro1 = ra * 2048 + ((((Pa & 127) ^ ((ra & 7) << 4))) >> 1);
  const int sro2 = rb * 2048 + ((((Pb & 127) ^ ((rb & 7) << 4))) >> 1);
  char* sd1 = LDS + w * 1024;
  char* sd2 = LDS + w * 1024 + 8192;

  f32x4 acc[8][4] = {};

#define GLDS(SRC, DST) __builtin_amdgcn_global_load_lds((gp_t)(const void*)(SRC), (lp_t)(void*)(DST), 16, 0, 0)
#define STG(MAT, ROWB, C, REG) { const u16* s_ = (MAT) + (long)(ROWB) * 2048 + (C) * 64; \
    GLDS(s_ + sro1, sd1 + (REG)); GLDS(s_ + sro2, sd2 + (REG)); }
#define RDB(DST, PAR) { _Pragma("unroll") for (int nf = 0; nf < 4; nf++){ \
      DST[nf*2]   = *(const bf16x8*)(BrdB + (PAR)*32768 + nf*2048 + aoff0); \
      DST[nf*2+1] = *(const bf16x8*)(BrdB + (PAR)*32768 + nf*2048 + aoff1); } }
#define RDA(PAR, MF) \
      a0 = *(const bf16x8*)(ArdB + (PAR)*32768 + (MF)*2048 + aoff0); \
      a1 = *(const bf16x8*)(ArdB + (PAR)*32768 + (MF)*2048 + aoff1); \
      a2 = *(const bf16x8*)(ArdB + (PAR)*32768 + (MF+1)*2048 + aoff0); \
      a3 = *(const bf16x8*)(ArdB + (PAR)*32768 + (MF+1)*2048 + aoff1);
#define BARW { __builtin_amdgcn_s_barrier(); \
      asm volatile("s_waitcnt lgkmcnt(0)" ::: "memory"); \
      __builtin_amdgcn_sched_barrier(0); }
#define MM(BF, MF) { __builtin_amdgcn_s_setprio(1); \
      _Pragma("unroll") for (int nf = 0; nf < 4; nf++){ \
        acc[MF][nf]   = __builtin_amdgcn_mfma_f32_16x16x32_bf16(a0, BF[nf*2],   acc[MF][nf],   0,0,0); \
        acc[MF][nf]   = __builtin_amdgcn_mfma_f32_16x16x32_bf16(a1, BF[nf*2+1], acc[MF][nf],   0,0,0); \
        acc[MF+1][nf] = __builtin_amdgcn_mfma_f32_16x16x32_bf16(a2, BF[nf*2],   acc[MF+1][nf], 0,0,0); \
        acc[MF+1][nf] = __builtin_amdgcn_mfma_f32_16x16x32_bf16(a3, BF[nf*2+1], acc[MF+1][nf], 0,0,0); } \
      __builtin_amdgcn_s_setprio(0); }

  STG(A,  m0,        0, 0);
  STG(A,  m0 + 128,  0, 16384);
  STG(Bm, n0s,       0, 65536);
  STG(Bm, n0s + 128, 0, 81920);
  STG(Bm, n0s,       1, 98304);
  STG(Bm, n0s + 128, 1, 114688);
  asm volatile("s_waitcnt vmcnt(4)" ::: "memory");
  __builtin_amdgcn_s_barrier();

  for (int i = 0; i < 16; ++i){
    const int c1 = 2 * i + 1;
    const int cn = 2 * i + 2;
    const bool nlast = (i < 15);
    bf16x8 b0[8], b1[8];
    bf16x8 a0, a1, a2, a3;

    RDB(b0, 0); RDA(0, 0);
    STG(A, m0, c1, 32768);
    BARW; MM(b0, 0);
    __builtin_amdgcn_s_barrier();

    RDA(0, 2);
    STG(A, m0 + 128, c1, 49152);
    BARW; MM(b0, 2);
    __builtin_amdgcn_s_barrier();

    RDA(0, 4);
    if (nlast) STG(Bm, n0s, cn, 65536);
    BARW; MM(b0, 4);
    __builtin_amdgcn_s_barrier();

    RDA(0, 6);
    if (nlast) STG(Bm, n0s + 128, cn, 81920);
    BARW; MM(b0, 6);
    if (nlast) { asm volatile("s_waitcnt vmcnt(4)" ::: "memory"); }
    else       { asm volatile("s_waitcnt vmcnt(0)" ::: "memory"); }
    __builtin_amdgcn_s_barrier();

    RDB(b1, 1); RDA(1, 0);
    if (nlast) STG(A, m0, cn, 0);
    BARW; MM(b1, 0);
    __builtin_amdgcn_s_barrier();

    RDA(1, 2);
    if (nlast) STG(A, m0 + 128, cn, 16384);
    BARW; MM(b1, 2);
    __builtin_amdgcn_s_barrier();

    RDA(1, 4);
    if (nlast) STG(Bm, n0s, cn + 1, 98304);
    BARW; MM(b1, 4);
    __builtin_amdgcn_s_barrier();

    RDA(1, 6);
    if (nlast) STG(Bm, n0s + 128, cn + 1, 114688);
    BARW; MM(b1, 6);
    if (nlast) { asm volatile("s_waitcnt vmcnt(4)" ::: "memory"); }
    __builtin_amdgcn_s_barrier();
  }

#undef MM
#undef BARW
#undef RDA
#undef RDB
#undef STG
#undef GLDS

  const int rbase = m0 + wm * 128 + ((l >> 4) << 2);
  const int cb2 = n0s + wn * 64 + (l & 15);
#pragma unroll
  for (int mf = 0; mf < 8; mf++){
#pragma unroll
    for (int nf = 0; nf < 4; nf++){
      const int nl = cb2 + nf * 16;
      const int h = nl >> 7, dd = nl & 127;
      if (which == 2){
        const int mm = rbase + mf * 16;
        const int b = mm >> 11, s = mm & 2047;
        const int bh = b * NH + h;
        ushort4 pkv = { f2b(acc[mf][nf][0]), f2b(acc[mf][nf][1]), f2b(acc[mf][nf][2]), f2b(acc[mf][nf][3]) };
        *(ushort4*)(vtb + ((long)bh * HD + dd) * FULLS + PASTN + s) = pkv;
#pragma unroll
        for (int r = 0; r < 4; r++){
          long idx = ((long)bh * FULLS + PASTN + s + r) * HD + dd;
          outv[idx] = acc[mf][nf][r];
        }
      } else if (which == 1){
#pragma unroll
        for (int r = 0; r < 4; r++){
          const int mm = rbase + mf * 16 + r;
          const int b = mm >> 11, s = mm & 2047;
          long idx = (((long)(b * NH + h)) * FULLS + PASTN + s) * HD + dd;
          float v = acc[mf][nf][r];
          kbb[idx] = f2b(v);
          outk[idx] = v;
        }
      } else {
#pragma unroll
        for (int r = 0; r < 4; r++){
          const int mm = rbase + mf * 16 + r;
          const int b = mm >> 11, s = mm & 2047;
          qb[(((long)(b * NH + h)) * SEQ + s) * HD + dd] = f2b(acc[mf][nf][r]);
        }
      }
    }
  }
}

// ---------------- O-projection bt-GEMM (fp32 out, row-major) ----------------
__global__ void k_gemm_o(const u16* __restrict__ A, const u16* __restrict__ Bm,
                         float* __restrict__ outf, int M, int N, int K)
{
  __shared__ u16 As[128 * 64];
  __shared__ u16 Bs[128 * 64];
  const int tid = threadIdx.x;
  const int w = tid >> 6, l = tid & 63;
  const int m0 = blockIdx.y * 128, n0 = blockIdx.x * 128;
  const int wr = w >> 1, wc = w & 1;
  const int lr = l & 15;
  const int lkb = (l >> 4) * 16;
  f32x4 acc[4][4] = {};

  for (int kt = 0; kt < K; kt += 64){
#pragma unroll
    for (int it = 0; it < 4; it++){
      int Pw = it * 4096 + w * 1024;
      int P = Pw + l * 16;
      int row = P >> 7, cb = P & 127;
      const u16* ga = A + (long)(m0 + row) * K + kt + (cb >> 1);
      __builtin_amdgcn_global_load_lds((gp_t)(const void*)ga, (lp_t)(void*)((char*)As + Pw), 16, 0, 0);
      const u16* gb = Bm + (long)(n0 + row) * K + kt + (cb >> 1);
      __builtin_amdgcn_global_load_lds((gp_t)(const void*)gb, (lp_t)(void*)((char*)Bs + Pw), 16, 0, 0);
    }
    __syncthreads();
#pragma unroll
    for (int kk = 0; kk < 2; kk++){
      bf16x8 af[4], bf[4];
#pragma unroll
      for (int i = 0; i < 4; i++){
        af[i] = *(const bf16x8*)((const char*)As + (wr * 64 + i * 16 + lr) * 128 + kk * 64 + lkb);
        bf[i] = *(const bf16x8*)((const char*)Bs + (wc * 64 + i * 16 + lr) * 128 + kk * 64 + lkb);
      }
#pragma unroll
      for (int i = 0; i < 4; i++)
#pragma unroll
        for (int j = 0; j < 4; j++)
          acc[i][j] = __builtin_amdgcn_mfma_f32_16x16x32_bf16(af[i], bf[j], acc[i][j], 0, 0, 0);
    }
    __syncthreads();
  }

  const int rbase = m0 + wr * 64 + ((l >> 4) << 2);
  const int cbase = n0 + wc * 64 + lr;
#pragma unroll
  for (int i = 0; i < 4; i++)
#pragma unroll
    for (int j = 0; j < 4; j++){
      const int nn = cbase + j * 16;
#pragma unroll
      for (int r = 0; r < 4; r++)
        outf[(long)(rbase + i * 16 + r) * N + nn] = acc[i][j][r];
    }
}

// ------- flash attention (unchanged) -------
__global__ __launch_bounds__(256, 2)
void k_attn(const u16* __restrict__ qb, const u16* __restrict__ kb,
            const u16* __restrict__ vtb, u16* __restrict__ ab)
{
  __shared__ u16 Ks[2][64 * 128];
  __shared__ u16 Vs[2][128 * 64];
  const int tid = threadIdx.x, w = tid >> 6, l = tid & 63;
  const int lq = l & 31, hi = l >> 5;
  const int dd0 = blockIdx.x;
  const int xcd = dd0 & 7;
  const int j   = dd0 >> 3;
  const int ja = j >> 5, jb = (j >> 1) & 15, jc = j & 1;
  const int bh  = xcd * 4 + 2 * ja + jc;
  const int q0b = ((ja ^ jc) ? (15 - jb) : jb) << 7;
  const int qbase = q0b + w * 32;
  const int qpos = PASTN + qbase + lq;
  const u16* qhead = qb + (long)bh * SEQ * HD;
  const u16* khead = kb + (long)bh * FULLS * HD;
  const u16* vhead = vtb + (long)bh * HD * FULLS;

  const float qscale = 0.08838834764831845f * 1.4426950408889634f;
  bf16x8 qf[8];
#pragma unroll
  for (int ks = 0; ks < 8; ks++){
    bf16x8 tq = *(const bf16x8*)(qhead + (long)(qbase + lq) * HD + ks * 16 + hi * 8);
#pragma unroll
    for (int jj = 0; jj < 8; jj++) tq[jj] = (short)f2b(b2f((u16)tq[jj]) * qscale);
    qf[ks] = tq;
  }

  const int kswz = (lq & 15) << 4;
  const int vswz = (lq & 7) << 4;
  const char* kaddr[8];
#pragma unroll
  for (int ks = 0; ks < 8; ks++)
    kaddr[ks] = (const char*)Ks + lq * 256 + ((ks * 32 + hi * 16) ^ kswz);
  const char* vaddr[4];
#pragma unroll
  for (int ks2 = 0; ks2 < 4; ks2++)
    vaddr[ks2] = (const char*)Vs + lq * 128 + ((ks2 * 32 + hi * 16) ^ vswz);

  int ksrcoff[4], vsrcoff[4];
#pragma unroll
  for (int it = 0; it < 4; it++){
    int P = it * 4096 + w * 1024 + l * 16;
    ksrcoff[it] = P ^ (((P >> 8) & 15) << 4);
    int row = P >> 7;
    int cb = (P & 127) ^ ((row & 7) << 4);
    vsrcoff[it] = row * 8192 + cb;
  }

  auto stageK = [&](int t, int bufo){
    const char* src = (const char*)khead + ((long)t << 14);
    char* dstb = (char*)Ks + bufo + w * 1024;
#pragma unroll
    for (int it = 0; it < 4; it++)
      __builtin_amdgcn_global_load_lds((gp_t)(const void*)(src + ksrcoff[it]),
                                       (lp_t)(void*)(dstb + it * 4096), 16, 0, 0);
  };
  auto stageV = [&](int t, int bufo){
    const char* src = (const char*)vhead + ((long)t << 7);
    char* dstb = (char*)Vs + bufo + w * 1024;
#pragma unroll
    for (int it = 0; it < 4; it++)
      __builtin_amdgcn_global_load_lds((gp_t)(const void*)(src + vsrcoff[it]),
                                       (lp_t)(void*)(dstb + it * 4096), 16, 0, 0);
  };

  f32x16 acc[4] = {};
  float m_run = -1e30f, l_run = 0.f;
  const int ntiles = (PASTN + q0b + 128) >> 6;

  auto finishPV = [&](f32x16& sp0, f32x16& sp1, int vbufo){
    float a0[8];
#pragma unroll
    for (int i = 0; i < 8; i++)
      a0[i] = fmaxf(fmaxf(sp0[i], sp0[i + 8]), fmaxf(sp1[i], sp1[i + 8]));
    float mx = fmaxf(fmaxf(fmaxf(a0[0], a0[1]), fmaxf(a0[2], a0[3])),
                     fmaxf(fmaxf(a0[4], a0[5]), fmaxf(a0[6], a0[7])));
    { float xa = mx, xb = mx;
      asm("v_permlane32_swap_b32 %0, %1" : "+v"(xa), "+v"(xb));
      mx = fmaxf(xa, xb); }

    if (!__all(mx <= m_run + 8.f)){
      float mnew = fmaxf(m_run, mx);
      float corr = __builtin_exp2f(m_run - mnew);
      m_run = mnew; l_run *= corr;
#pragma unroll
      for (int r = 0; r < 16; r++){
        int qlr = (r & 3) + 8 * (r >> 2) + 4 * hi;
        float cr = __shfl(corr, qlr);
#pragma unroll
        for (int d2 = 0; d2 < 4; d2++) acc[d2][r] *= cr;
      }
    }

    float rs = 0.f;
#pragma unroll
    for (int r = 0; r < 16; r++){
      sp0[r] = __builtin_exp2f(sp0[r] - m_run); rs += sp0[r];
      sp1[r] = __builtin_exp2f(sp1[r] - m_run); rs += sp1[r];
    }
    { float ra = rs, rb = rs;
      asm("v_permlane32_swap_b32 %0, %1" : "+v"(ra), "+v"(rb));
      l_run += ra + rb; }

    bf16x8 pfrag[4];
#pragma unroll
    for (int kb2 = 0; kb2 < 2; kb2++){
      const f32x16& sp = kb2 ? sp1 : sp0;
#pragma unroll
      for (int half = 0; half < 2; half++){
        const int h8 = half * 8;
        u32 A0 = cvtpk(sp[h8 + 0], sp[h8 + 1]);
        u32 A1 = cvtpk(sp[h8 + 2], sp[h8 + 3]);
        u32 B0 = cvtpk(sp[h8 + 4], sp[h8 + 5]);
        u32 B1 = cvtpk(sp[h8 + 6], sp[h8 + 7]);
        asm("v_permlane32_swap_b32 %0, %1" : "+v"(A0), "+v"(B0));
        asm("v_permlane32_swap_b32 %0, %1" : "+v"(A1), "+v"(B1));
        union { u32 wd[4]; bf16x8 v; } F;
        F.wd[0] = A0; F.wd[1] = A1; F.wd[2] = B0; F.wd[3] = B1;
        pfrag[kb2 * 2 + half] = F.v;
      }
    }

    __builtin_amdgcn_s_setprio(1);
#pragma unroll
    for (int ks2 = 0; ks2 < 4; ks2++)
#pragma unroll
      for (int d2 = 0; d2 < 4; d2++){
        bf16x8 vf = *(const bf16x8*)(vaddr[ks2] + vbufo + d2 * 4096);
        acc[d2] = __builtin_amdgcn_mfma_f32_32x32x16_bf16(pfrag[ks2], vf, acc[d2], 0, 0, 0);
      }
    __builtin_amdgcn_s_setprio(0);
  };

#define QKT_MASK(T_, BUFC_, SC0_, SC1_)                                        \
  {                                                                            \
    SC0_ = zero16(); SC1_ = zero16();                                          \
    __builtin_amdgcn_s_setprio(1);                                             \
    _Pragma("unroll")                                                          \
    for (int ks = 0; ks < 8; ks++){                                            \
      bf16x8 kf0 = *(const bf16x8*)(kaddr[ks] + (BUFC_));                      \
      bf16x8 kf1 = *(const bf16x8*)(kaddr[ks] + (BUFC_) + 8192);               \
      SC0_ = __builtin_amdgcn_mfma_f32_32x32x16_bf16(kf0, qf[ks], SC0_, 0,0,0);\
      SC1_ = __builtin_amdgcn_mfma_f32_32x32x16_bf16(kf1, qf[ks], SC1_, 0,0,0);\
    }                                                                          \
    __builtin_amdgcn_s_setprio(0);                                             \
    const int kvb_ = (T_) * 64;                                                \
    if (kvb_ + 63 > PASTN + qbase){                                            \
      _Pragma("unroll")                                                        \
      for (int r = 0; r < 16; r++){                                            \
        int key = kvb_ + (r & 3) + 8 * (r >> 2) + 4 * hi;                      \
        if (key > qpos) SC0_[r] = -1e30f;                                      \
        if (key + 32 > qpos) SC1_[r] = -1e30f;                                 \
      }                                                                        \
    }                                                                          \
  }

#define STEP(T_, BUFC_, SP0_, SP1_, SC0_, SC1_)                                \
  {                                                                            \
    if ((T_) + 1 < ntiles) stageK((T_) + 1, (BUFC_) ^ 16384);                  \
    QKT_MASK(T_, BUFC_, SC0_, SC1_);                                           \
    finishPV(SP0_, SP1_, (BUFC_) ^ 16384);                                     \
    __syncthreads();                                                           \
    if ((T_) + 1 < ntiles) stageV((T_) + 1, (BUFC_) ^ 16384);                  \
  }

  f32x16 PA0, PA1, PB0, PB1;

  stageK(0, 0); stageV(0, 0);
  __syncthreads();

  stageK(1, 16384);
  QKT_MASK(0, 0, PA0, PA1);
  __syncthreads();
  stageV(1, 16384);

  for (int t = 1; t + 2 < ntiles; t += 2){
    STEP(t,     16384, PA0, PA1, PB0, PB1);
    STEP(t + 1, 0,     PB0, PB1, PA0, PA1);
  }
  STEP(ntiles - 1, 16384, PA0, PA1, PB0, PB1);
  finishPV(PB0, PB1, 16384);

#undef STEP
#undef QKT_MASK

  float inv = 1.0f / l_run;
  const int b = bh >> 4, h = bh & 15;
#pragma unroll
  for (int r = 0; r < 16; r++){
    int qlr = (r & 3) + 8 * (r >> 2) + 4 * hi;
    float ir = __shfl(inv, qlr);
    long rowbase = ((long)b * SEQ + (qbase + qlr)) * DM + h * HD;
#pragma unroll
    for (int d2 = 0; d2 < 4; d2++)
      ab[rowbase + d2 * 32 + lq] = f2b(acc[d2][r] * ir);
  }
}

extern "C" void kernel_launch(void* const* d_in, const int* in_sizes, int n_in,
                              void* d_out, int out_size, void* d_ws, size_t ws_size,
                              hipStream_t stream) {
  const float* x      = (const float*)d_in[0];
  const float* past_k = (const float*)d_in[1];
  const float* past_v = (const float*)d_in[2];
  const float* Wq     = (const float*)d_in[3];
  const float* Wk     = (const float*)d_in[4];
  const float* Wv     = (const float*)d_in[5];
  const float* Wo     = (const float*)d_in[6];

  float* out  = (float*)d_out;
  float* outk = out + 8388608;       // B*S*DM
  float* outv = out + 25165824;      // + B*NH*FULLS*HD

  char* ws = (char*)d_ws;
  u16* wqb = (u16*)ws;
  u16* wkb = (u16*)(ws + 8388608);
  u16* wvb = (u16*)(ws + 16777216);
  u16* wob = (u16*)(ws + 25165824);
  u16* xb  = (u16*)(ws + 33554432);
  u16* qb  = (u16*)(ws + 50331648);
  u16* kb  = (u16*)(ws + 67108864);
  u16* vtb = (u16*)(ws + 100663296);
  u16* ab  = xb;                     // alias: x consumed before attn writes

  k_conv5<<<2048, 256, 0, stream>>>(x, Wq, Wk, Wv, Wo, xb, wqb, wkb, wvb, wob);

  k_qkv_fused<<<512, 512, 0, stream>>>(xb, wqb, wkb, wvb,
                                       qb, kb, vtb, outk, outv,
                                       past_k, past_v);

  k_attn<<<512, 256, 0, stream>>>(qb, kb, vtb, ab);

  k_gemm_o<<<dim3(16, 32), 256, 0, stream>>>(ab, wob, out, 4096, 2048, 2048);
}

// Round 10
// 354.906 us; speedup vs baseline: 1.4330x; 1.0427x over previous
//
#include <hip/hip_runtime.h>
#include <hip/hip_bf16.h>
#include <stdint.h>

typedef __attribute__((ext_vector_type(8))) short bf16x8;
typedef __attribute__((ext_vector_type(4))) float f32x4;
typedef __attribute__((ext_vector_type(16))) float f32x16;
typedef unsigned short u16;
typedef unsigned int u32;
typedef const __attribute__((address_space(1))) u32* gp_t;
typedef __attribute__((address_space(3))) u32* lp_t;

#define HD 128
#define NH 16
#define SEQ 2048
#define PASTN 2048
#define FULLS 4096
#define DM 2048

__device__ __forceinline__ u16 f2b(float f){
  union { float f; u32 u; } v; v.f = f;
  return (u16)((v.u + 0x7fffu + ((v.u >> 16) & 1u)) >> 16);
}
__device__ __forceinline__ float b2f(u16 b){
  union { u32 u; float f; } v; v.u = ((u32)b) << 16;
  return v.f;
}
__device__ __forceinline__ u32 cvtpk(float lo, float hi){
  u32 r; asm("v_cvt_pk_bf16_f32 %0, %1, %2" : "=v"(r) : "v"(lo), "v"(hi)); return r;
}
__device__ __forceinline__ f32x16 zero16(){ f32x16 z = {}; return z; }

// ------- fused fp32->bf16 convert of x, Wq, Wk, Wv, Wo (one launch) -------
__global__ void k_conv5(const float* __restrict__ sx,
                        const float* __restrict__ s1, const float* __restrict__ s2,
                        const float* __restrict__ s3, const float* __restrict__ s4,
                        u16* __restrict__ dx,
                        u16* __restrict__ d1, u16* __restrict__ d2,
                        u16* __restrict__ d3, u16* __restrict__ d4)
{
  const int total = 2097152 + 4 * 1048576;
  int i = blockIdx.x * blockDim.x + threadIdx.x;
  int stride = gridDim.x * blockDim.x;
  for (; i < total; i += stride){
    const float* s; u16* d; int off;
    if (i < 2097152){ s = sx; d = dx; off = i; }
    else {
      int t = i - 2097152;
      int seg = t >> 20; off = t & 1048575;
      s = (seg == 0) ? s1 : (seg == 1) ? s2 : (seg == 2) ? s3 : s4;
      d = (seg == 0) ? d1 : (seg == 1) ? d2 : (seg == 2) ? d3 : d4;
    }
    float4 v = ((const float4*)s)[off];
    ushort4 o = { f2b(v.x), f2b(v.y), f2b(v.z), f2b(v.w) };
    ((ushort4*)d)[off] = o;
  }
}

// ==== fused QKV bt-GEMM (256^2 8-phase) + past-KV copy blocks (unchanged) ====
__global__ __launch_bounds__(512, 1)
void k_qkv_fused(const u16* __restrict__ A,
                 const u16* __restrict__ Bq, const u16* __restrict__ Bk,
                 const u16* __restrict__ Bv,
                 u16* __restrict__ qb, u16* __restrict__ kbb,
                 u16* __restrict__ vtb,
                 float* __restrict__ outk, float* __restrict__ outv,
                 const float* __restrict__ pk, const float* __restrict__ pv)
{
  __shared__ char LDS[131072];
  const int bx = blockIdx.x;
  const int tid = threadIdx.x;

  if (bx >= 384){
    if (bx < 448){
      for (int i = (bx - 384) * 512 + tid; i < 2097152; i += 32768){
        int g = i * 4;
        int c = g & 127;
        int r = g >> 7;
        int bh = r >> 11;
        int s = r & 2047;
        long dst = ((long)bh * FULLS + s) * HD + c;
        float4 v = ((const float4*)pk)[i];
        *(float4*)(outk + dst) = v;
        ushort4 o = { f2b(v.x), f2b(v.y), f2b(v.z), f2b(v.w) };
        *(ushort4*)(kbb + dst) = o;
      }
    } else {
      float* ldsF = (float*)LDS;              // [64][129] padded
      for (int cc = 0; cc < 16; cc++){
        int c = ((bx - 448) << 4) + cc;
        int bh = c >> 5, s0 = (c & 31) << 6;
        const float* src = pv + ((long)bh * PASTN + s0) * HD;
        float* dsv = outv + ((long)bh * FULLS + s0) * HD;
#pragma unroll
        for (int p = 0; p < 4; p++){
          int idx = tid + p * 512;
          int row = idx >> 5, c4 = (idx & 31) << 2;
          float4 v = *(const float4*)(src + row * HD + c4);
          *(float4*)(dsv + row * HD + c4) = v;
          ldsF[row * 129 + c4 + 0] = v.x;
          ldsF[row * 129 + c4 + 1] = v.y;
          ldsF[row * 129 + c4 + 2] = v.z;
          ldsF[row * 129 + c4 + 3] = v.w;
        }
        __syncthreads();
        int d = tid >> 2, sb = (tid & 3) << 4;
        u16* dst = vtb + ((long)bh * HD + d) * FULLS + s0 + sb;
#pragma unroll
        for (int g = 0; g < 4; g++){
          ushort4 o = { f2b(ldsF[(sb + g * 4 + 0) * 129 + d]),
                        f2b(ldsF[(sb + g * 4 + 1) * 129 + d]),
                        f2b(ldsF[(sb + g * 4 + 2) * 129 + d]),
                        f2b(ldsF[(sb + g * 4 + 3) * 129 + d]) };
          *(ushort4*)(dst + g * 4) = o;
        }
        __syncthreads();
      }
    }
    return;
  }

  const int w = tid >> 6, l = tid & 63;
  const int wm = w >> 2, wn = w & 3;
  const int which = bx >> 7;
  const int r0 = bx & 127;
  const int m0 = (r0 & 15) * 256;
  const int n0s = (r0 >> 4) * 256;
  const u16* Bm = (which == 0) ? Bq : (which == 1) ? Bk : Bv;

  const int aoff0 = (((l >> 4) * 16) ^ ((l & 7) << 4));
  const int aoff1 = ((64 + (l >> 4) * 16) ^ ((l & 7) << 4));
  const char* ArdB = LDS + wm * 16384 + (l & 15) * 128;
  const char* BrdB = LDS + 65536 + (wn >> 1) * 16384 + (wn & 1) * 8192 + (l & 15) * 128;

  const int Pa = tid * 16, Pb = tid * 16 + 8192;
  const int ra = Pa >> 7, rb = Pb >> 7;
  const int sro1 = ra * 2048 + ((((Pa & 127) ^ ((ra & 7) << 4))) >> 1);
  const int sro2 = rb * 2048 + ((((Pb & 127) ^ ((rb & 7) << 4))) >> 1);
  char* sd1 = LDS + w * 1024;
  char* sd2 = LDS + w * 1024 + 8192;

  f32x4 acc[8][4] = {};

#define GLDS(SRC, DST) __builtin_amdgcn_global_load_lds((gp_t)(const void*)(SRC), (lp_t)(void*)(DST), 16, 0, 0)
#define STG(MAT, ROWB, C, REG) { const u16* s_ = (MAT) + (long)(ROWB) * 2048 + (C) * 64; \
    GLDS(s_ + sro1, sd1 + (REG)); GLDS(s_ + sro2, sd2 + (REG)); }
#define RDB(DST, PAR) { _Pragma("unroll") for (int nf = 0; nf < 4; nf++){ \
      DST[nf*2]   = *(const bf16x8*)(BrdB + (PAR)*32768 + nf*2048 + aoff0); \
      DST[nf*2+1] = *(const bf16x8*)(BrdB + (PAR)*32768 + nf*2048 + aoff1); } }
#define RDA(PAR, MF) \
      a0 = *(const bf16x8*)(ArdB + (PAR)*32768 + (MF)*2048 + aoff0); \
      a1 = *(const bf16x8*)(ArdB + (PAR)*32768 + (MF)*2048 + aoff1); \
      a2 = *(const bf16x8*)(ArdB + (PAR)*32768 + (MF+1)*2048 + aoff0); \
      a3 = *(const bf16x8*)(ArdB + (PAR)*32768 + (MF+1)*2048 + aoff1);
#define BARW { __builtin_amdgcn_s_barrier(); \
      asm volatile("s_waitcnt lgkmcnt(0)" ::: "memory"); \
      __builtin_amdgcn_sched_barrier(0); }
#define MM(BF, MF) { __builtin_amdgcn_s_setprio(1); \
      _Pragma("unroll") for (int nf = 0; nf < 4; nf++){ \
        acc[MF][nf]   = __builtin_amdgcn_mfma_f32_16x16x32_bf16(a0, BF[nf*2],   acc[MF][nf],   0,0,0); \
        acc[MF][nf]   = __builtin_amdgcn_mfma_f32_16x16x32_bf16(a1, BF[nf*2+1], acc[MF][nf],   0,0,0); \
        acc[MF+1][nf] = __builtin_amdgcn_mfma_f32_16x16x32_bf16(a2, BF[nf*2],   acc[MF+1][nf], 0,0,0); \
        acc[MF+1][nf] = __builtin_amdgcn_mfma_f32_16x16x32_bf16(a3, BF[nf*2+1], acc[MF+1][nf], 0,0,0); } \
      __builtin_amdgcn_s_setprio(0); }

  STG(A,  m0,        0, 0);
  STG(A,  m0 + 128,  0, 16384);
  STG(Bm, n0s,       0, 65536);
  STG(Bm, n0s + 128, 0, 81920);
  STG(Bm, n0s,       1, 98304);
  STG(Bm, n0s + 128, 1, 114688);
  asm volatile("s_waitcnt vmcnt(4)" ::: "memory");
  __builtin_amdgcn_s_barrier();

  for (int i = 0; i < 16; ++i){
    const int c1 = 2 * i + 1;
    const int cn = 2 * i + 2;
    const bool nlast = (i < 15);
    bf16x8 b0[8], b1[8];
    bf16x8 a0, a1, a2, a3;

    RDB(b0, 0); RDA(0, 0);
    STG(A, m0, c1, 32768);
    BARW; MM(b0, 0);
    __builtin_amdgcn_s_barrier();

    RDA(0, 2);
    STG(A, m0 + 128, c1, 49152);
    BARW; MM(b0, 2);
    __builtin_amdgcn_s_barrier();

    RDA(0, 4);
    if (nlast) STG(Bm, n0s, cn, 65536);
    BARW; MM(b0, 4);
    __builtin_amdgcn_s_barrier();

    RDA(0, 6);
    if (nlast) STG(Bm, n0s + 128, cn, 81920);
    BARW; MM(b0, 6);
    if (nlast) { asm volatile("s_waitcnt vmcnt(4)" ::: "memory"); }
    else       { asm volatile("s_waitcnt vmcnt(0)" ::: "memory"); }
    __builtin_amdgcn_s_barrier();

    RDB(b1, 1); RDA(1, 0);
    if (nlast) STG(A, m0, cn, 0);
    BARW; MM(b1, 0);
    __builtin_amdgcn_s_barrier();

    RDA(1, 2);
    if (nlast) STG(A, m0 + 128, cn, 16384);
    BARW; MM(b1, 2);
    __builtin_amdgcn_s_barrier();

    RDA(1, 4);
    if (nlast) STG(Bm, n0s, cn + 1, 98304);
    BARW; MM(b1, 4);
    __builtin_amdgcn_s_barrier();

    RDA(1, 6);
    if (nlast) STG(Bm, n0s + 128, cn + 1, 114688);
    BARW; MM(b1, 6);
    if (nlast) { asm volatile("s_waitcnt vmcnt(4)" ::: "memory"); }
    __builtin_amdgcn_s_barrier();
  }

#undef MM
#undef BARW
#undef RDA
#undef RDB
#undef STG
#undef GLDS

  const int rbase = m0 + wm * 128 + ((l >> 4) << 2);
  const int cb2 = n0s + wn * 64 + (l & 15);
#pragma unroll
  for (int mf = 0; mf < 8; mf++){
#pragma unroll
    for (int nf = 0; nf < 4; nf++){
      const int nl = cb2 + nf * 16;
      const int h = nl >> 7, dd = nl & 127;
      if (which == 2){
        const int mm = rbase + mf * 16;
        const int b = mm >> 11, s = mm & 2047;
        const int bh = b * NH + h;
        ushort4 pkv = { f2b(acc[mf][nf][0]), f2b(acc[mf][nf][1]), f2b(acc[mf][nf][2]), f2b(acc[mf][nf][3]) };
        *(ushort4*)(vtb + ((long)bh * HD + dd) * FULLS + PASTN + s) = pkv;
#pragma unroll
        for (int r = 0; r < 4; r++){
          long idx = ((long)bh * FULLS + PASTN + s + r) * HD + dd;
          outv[idx] = acc[mf][nf][r];
        }
      } else if (which == 1){
#pragma unroll
        for (int r = 0; r < 4; r++){
          const int mm = rbase + mf * 16 + r;
          const int b = mm >> 11, s = mm & 2047;
          long idx = (((long)(b * NH + h)) * FULLS + PASTN + s) * HD + dd;
          float v = acc[mf][nf][r];
          kbb[idx] = f2b(v);
          outk[idx] = v;
        }
      } else {
#pragma unroll
        for (int r = 0; r < 4; r++){
          const int mm = rbase + mf * 16 + r;
          const int b = mm >> 11, s = mm & 2047;
          qb[(((long)(b * NH + h)) * SEQ + s) * HD + dd] = f2b(acc[mf][nf][r]);
        }
      }
    }
  }
}

// ==== O-projection: 8-phase, BM=256 BN=128, grid 16x16=256 = 1 full wave ====
// LDS 96KB: A[2par][2half][128][64] @0 (64KB), B[2par][128][64] @65536 (32KB).
// Ring: ph1,2=A(c1); ph3=B(c0+2); ph5,6=A(c0+2); ph7=B(c1+2).
// Invariant: 2 loads (latest B) outstanding at iter start -> vmcnt(2) @ph4/ph8.
__global__ __launch_bounds__(512, 1)
void k_gemm_o8(const u16* __restrict__ A, const u16* __restrict__ Bm,
               float* __restrict__ outf)
{
  __shared__ char LDS[98304];
  const int tid = threadIdx.x, w = tid >> 6, l = tid & 63;
  const int wm = w >> 2, wn = w & 3;
  const int m0 = (blockIdx.x & 15) * 256;
  const int n0 = (blockIdx.x >> 4) * 128;

  const int aoff0 = (((l >> 4) * 16) ^ ((l & 7) << 4));
  const int aoff1 = ((64 + (l >> 4) * 16) ^ ((l & 7) << 4));
  const char* ArdB = LDS + wm * 16384 + (l & 15) * 128;
  const char* BrdB = LDS + 65536 + wn * 4096 + (l & 15) * 128;

  const int Pa = tid * 16, Pb = tid * 16 + 8192;
  const int ra = Pa >> 7, rb = Pb >> 7;
  const int sro1 = ra * 2048 + ((((Pa & 127) ^ ((ra & 7) << 4))) >> 1);
  const int sro2 = rb * 2048 + ((((Pb & 127) ^ ((rb & 7) << 4))) >> 1);
  char* sd1 = LDS + w * 1024;
  char* sd2 = LDS + w * 1024 + 8192;

  f32x4 acc[8][2] = {};

#define GLDS(SRC, DST) __builtin_amdgcn_global_load_lds((gp_t)(const void*)(SRC), (lp_t)(void*)(DST), 16, 0, 0)
#define STG(MAT, ROWB, C, REG) { const u16* s_ = (MAT) + (long)(ROWB) * 2048 + (C) * 64; \
    GLDS(s_ + sro1, sd1 + (REG)); GLDS(s_ + sro2, sd2 + (REG)); }
#define RDB2(DST, PAR) { _Pragma("unroll") for (int nf = 0; nf < 2; nf++){ \
      DST[nf*2]   = *(const bf16x8*)(BrdB + (PAR)*16384 + nf*2048 + aoff0); \
      DST[nf*2+1] = *(const bf16x8*)(BrdB + (PAR)*16384 + nf*2048 + aoff1); } }
#define RDA(PAR, MF) \
      a0 = *(const bf16x8*)(ArdB + (PAR)*32768 + (MF)*2048 + aoff0); \
      a1 = *(const bf16x8*)(ArdB + (PAR)*32768 + (MF)*2048 + aoff1); \
      a2 = *(const bf16x8*)(ArdB + (PAR)*32768 + (MF+1)*2048 + aoff0); \
      a3 = *(const bf16x8*)(ArdB + (PAR)*32768 + (MF+1)*2048 + aoff1);
#define BARW { __builtin_amdgcn_s_barrier(); \
      asm volatile("s_waitcnt lgkmcnt(0)" ::: "memory"); \
      __builtin_amdgcn_sched_barrier(0); }
#define MM2(BF, MF) { __builtin_amdgcn_s_setprio(1); \
      _Pragma("unroll") for (int nf = 0; nf < 2; nf++){ \
        acc[MF][nf]   = __builtin_amdgcn_mfma_f32_16x16x32_bf16(a0, BF[nf*2],   acc[MF][nf],   0,0,0); \
        acc[MF][nf]   = __builtin_amdgcn_mfma_f32_16x16x32_bf16(a1, BF[nf*2+1], acc[MF][nf],   0,0,0); \
        acc[MF+1][nf] = __builtin_amdgcn_mfma_f32_16x16x32_bf16(a2, BF[nf*2],   acc[MF+1][nf], 0,0,0); \
        acc[MF+1][nf] = __builtin_amdgcn_mfma_f32_16x16x32_bf16(a3, BF[nf*2+1], acc[MF+1][nf], 0,0,0); } \
      __builtin_amdgcn_s_setprio(0); }

  // prologue: A0 (2 units), B0, B1 -> 8 loads; vmcnt(2) leaves B1 in flight
  STG(A,  m0,       0, 0);
  STG(A,  m0 + 128, 0, 16384);
  STG(Bm, n0,       0, 65536);
  STG(Bm, n0,       1, 81920);
  asm volatile("s_waitcnt vmcnt(2)" ::: "memory");
  __builtin_amdgcn_s_barrier();

  for (int i = 0; i < 16; ++i){
    const int c1 = 2 * i + 1;
    const int cn = 2 * i + 2;
    const bool nlast = (i < 15);
    bf16x8 b0[4], b1[4];
    bf16x8 a0, a1, a2, a3;

    RDB2(b0, 0); RDA(0, 0);
    STG(A, m0, c1, 32768);
    BARW; MM2(b0, 0);
    __builtin_amdgcn_s_barrier();

    RDA(0, 2);
    STG(A, m0 + 128, c1, 49152);
    BARW; MM2(b0, 2);
    __builtin_amdgcn_s_barrier();

    RDA(0, 4);
    if (nlast) STG(Bm, n0, cn, 65536);
    BARW; MM2(b0, 4);
    __builtin_amdgcn_s_barrier();

    RDA(0, 6);
    BARW; MM2(b0, 6);
    if (nlast) { asm volatile("s_waitcnt vmcnt(2)" ::: "memory"); }
    else       { asm volatile("s_waitcnt vmcnt(0)" ::: "memory"); }
    __builtin_amdgcn_s_barrier();

    RDB2(b1, 1); RDA(1, 0);
    if (nlast) STG(A, m0, cn, 0);
    BARW; MM2(b1, 0);
    __builtin_amdgcn_s_barrier();

    RDA(1, 2);
    if (nlast) STG(A, m0 + 128, cn, 16384);
    BARW; MM2(b1, 2);
    __builtin_amdgcn_s_barrier();

    RDA(1, 4);
    if (nlast) STG(Bm, n0, cn + 1, 81920);
    BARW; MM2(b1, 4);
    __builtin_amdgcn_s_barrier();

    RDA(1, 6);
    BARW; MM2(b1, 6);
    if (nlast) { asm volatile("s_waitcnt vmcnt(2)" ::: "memory"); }
    __builtin_amdgcn_s_barrier();
  }

#undef MM2
#undef BARW
#undef RDA
#undef RDB2
#undef STG
#undef GLDS

  const int rbase = m0 + wm * 128 + ((l >> 4) << 2);
  const int cb2 = n0 + wn * 32 + (l & 15);
#pragma unroll
  for (int mf = 0; mf < 8; mf++)
#pragma unroll
    for (int nf = 0; nf < 2; nf++){
      const int nn = cb2 + nf * 16;
#pragma unroll
      for (int r = 0; r < 4; r++)
        outf[(long)(rbase + mf * 16 + r) * DM + nn] = acc[mf][nf][r];
    }
}

// ------- flash attention (unchanged) -------
__global__ __launch_bounds__(256, 2)
void k_attn(const u16* __restrict__ qb, const u16* __restrict__ kb,
            const u16* __restrict__ vtb, u16* __restrict__ ab)
{
  __shared__ u16 Ks[2][64 * 128];
  __shared__ u16 Vs[2][128 * 64];
  const int tid = threadIdx.x, w = tid >> 6, l = tid & 63;
  const int lq = l & 31, hi = l >> 5;
  const int dd0 = blockIdx.x;
  const int xcd = dd0 & 7;
  const int j   = dd0 >> 3;
  const int ja = j >> 5, jb = (j >> 1) & 15, jc = j & 1;
  const int bh  = xcd * 4 + 2 * ja + jc;
  const int q0b = ((ja ^ jc) ? (15 - jb) : jb) << 7;
  const int qbase = q0b + w * 32;
  const int qpos = PASTN + qbase + lq;
  const u16* qhead = qb + (long)bh * SEQ * HD;
  const u16* khead = kb + (long)bh * FULLS * HD;
  const u16* vhead = vtb + (long)bh * HD * FULLS;

  const float qscale = 0.08838834764831845f * 1.4426950408889634f;
  bf16x8 qf[8];
#pragma unroll
  for (int ks = 0; ks < 8; ks++){
    bf16x8 tq = *(const bf16x8*)(qhead + (long)(qbase + lq) * HD + ks * 16 + hi * 8);
#pragma unroll
    for (int jj = 0; jj < 8; jj++) tq[jj] = (short)f2b(b2f((u16)tq[jj]) * qscale);
    qf[ks] = tq;
  }

  const int kswz = (lq & 15) << 4;
  const int vswz = (lq & 7) << 4;
  const char* kaddr[8];
#pragma unroll
  for (int ks = 0; ks < 8; ks++)
    kaddr[ks] = (const char*)Ks + lq * 256 + ((ks * 32 + hi * 16) ^ kswz);
  const char* vaddr[4];
#pragma unroll
  for (int ks2 = 0; ks2 < 4; ks2++)
    vaddr[ks2] = (const char*)Vs + lq * 128 + ((ks2 * 32 + hi * 16) ^ vswz);

  int ksrcoff[4], vsrcoff[4];
#pragma unroll
  for (int it = 0; it < 4; it++){
    int P = it * 4096 + w * 1024 + l * 16;
    ksrcoff[it] = P ^ (((P >> 8) & 15) << 4);
    int row = P >> 7;
    int cb = (P & 127) ^ ((row & 7) << 4);
    vsrcoff[it] = row * 8192 + cb;
  }

  auto stageK = [&](int t, int bufo){
    const char* src = (const char*)khead + ((long)t << 14);
    char* dstb = (char*)Ks + bufo + w * 1024;
#pragma unroll
    for (int it = 0; it < 4; it++)
      __builtin_amdgcn_global_load_lds((gp_t)(const void*)(src + ksrcoff[it]),
                                       (lp_t)(void*)(dstb + it * 4096), 16, 0, 0);
  };
  auto stageV = [&](int t, int bufo){
    const char* src = (const char*)vhead + ((long)t << 7);
    char* dstb = (char*)Vs + bufo + w * 1024;
#pragma unroll
    for (int it = 0; it < 4; it++)
      __builtin_amdgcn_global_load_lds((gp_t)(const void*)(src + vsrcoff[it]),
                                       (lp_t)(void*)(dstb + it * 4096), 16, 0, 0);
  };

  f32x16 acc[4] = {};
  float m_run = -1e30f, l_run = 0.f;
  const int ntiles = (PASTN + q0b + 128) >> 6;

  auto finishPV = [&](f32x16& sp0, f32x16& sp1, int vbufo){
    float a0[8];
#pragma unroll
    for (int i = 0; i < 8; i++)
      a0[i] = fmaxf(fmaxf(sp0[i], sp0[i + 8]), fmaxf(sp1[i], sp1[i + 8]));
    float mx = fmaxf(fmaxf(fmaxf(a0[0], a0[1]), fmaxf(a0[2], a0[3])),
                     fmaxf(fmaxf(a0[4], a0[5]), fmaxf(a0[6], a0[7])));
    { float xa = mx, xb = mx;
      asm("v_permlane32_swap_b32 %0, %1" : "+v"(xa), "+v"(xb));
      mx = fmaxf(xa, xb); }

    if (!__all(mx <= m_run + 8.f)){
      float mnew = fmaxf(m_run, mx);
      float corr = __builtin_exp2f(m_run - mnew);
      m_run = mnew; l_run *= corr;
#pragma unroll
      for (int r = 0; r < 16; r++){
        int qlr = (r & 3) + 8 * (r >> 2) + 4 * hi;
        float cr = __shfl(corr, qlr);
#pragma unroll
        for (int d2 = 0; d2 < 4; d2++) acc[d2][r] *= cr;
      }
    }

    float rs = 0.f;
#pragma unroll
    for (int r = 0; r < 16; r++){
      sp0[r] = __builtin_exp2f(sp0[r] - m_run); rs += sp0[r];
      sp1[r] = __builtin_exp2f(sp1[r] - m_run); rs += sp1[r];
    }
    { float ra = rs, rb = rs;
      asm("v_permlane32_swap_b32 %0, %1" : "+v"(ra), "+v"(rb));
      l_run += ra + rb; }

    bf16x8 pfrag[4];
#pragma unroll
    for (int kb2 = 0; kb2 < 2; kb2++){
      const f32x16& sp = kb2 ? sp1 : sp0;
#pragma unroll
      for (int half = 0; half < 2; half++){
        const int h8 = half * 8;
        u32 A0 = cvtpk(sp[h8 + 0], sp[h8 + 1]);
        u32 A1 = cvtpk(sp[h8 + 2], sp[h8 + 3]);
        u32 B0 = cvtpk(sp[h8 + 4], sp[h8 + 5]);
        u32 B1 = cvtpk(sp[h8 + 6], sp[h8 + 7]);
        asm("v_permlane32_swap_b32 %0, %1" : "+v"(A0), "+v"(B0));
        asm("v_permlane32_swap_b32 %0, %1" : "+v"(A1), "+v"(B1));
        union { u32 wd[4]; bf16x8 v; } F;
        F.wd[0] = A0; F.wd[1] = A1; F.wd[2] = B0; F.wd[3] = B1;
        pfrag[kb2 * 2 + half] = F.v;
      }
    }

    __builtin_amdgcn_s_setprio(1);
#pragma unroll
    for (int ks2 = 0; ks2 < 4; ks2++)
#pragma unroll
      for (int d2 = 0; d2 < 4; d2++){
        bf16x8 vf = *(const bf16x8*)(vaddr[ks2] + vbufo + d2 * 4096);
        acc[d2] = __builtin_amdgcn_mfma_f32_32x32x16_bf16(pfrag[ks2], vf, acc[d2], 0, 0, 0);
      }
    __builtin_amdgcn_s_setprio(0);
  };

#define QKT_MASK(T_, BUFC_, SC0_, SC1_)                                        \
  {                                                                            \
    SC0_ = zero16(); SC1_ = zero16();                                          \
    __builtin_amdgcn_s_setprio(1);                                             \
    _Pragma("unroll")                                                          \
    for (int ks = 0; ks < 8; ks++){                                            \
      bf16x8 kf0 = *(const bf16x8*)(kaddr[ks] + (BUFC_));                      \
      bf16x8 kf1 = *(const bf16x8*)(kaddr[ks] + (BUFC_) + 8192);               \
      SC0_ = __builtin_amdgcn_mfma_f32_32x32x16_bf16(kf0, qf[ks], SC0_, 0,0,0);\
      SC1_ = __builtin_amdgcn_mfma_f32_32x32x16_bf16(kf1, qf[ks], SC1_, 0,0,0);\
    }                                                                          \
    __builtin_amdgcn_s_setprio(0);                                             \
    const int kvb_ = (T_) * 64;                                                \
    if (kvb_ + 63 > PASTN + qbase){                                            \
      _Pragma("unroll")                                                        \
      for (int r = 0; r < 16; r++){                                            \
        int key = kvb_ + (r & 3) + 8 * (r >> 2) + 4 * hi;                      \
        if (key > qpos) SC0_[r] = -1e30f;                                      \
        if (key + 32 > qpos) SC1_[r] = -1e30f;                                 \
      }                                                                        \
    }                                                                          \
  }

#define STEP(T_, BUFC_, SP0_, SP1_, SC0_, SC1_)                                \
  {                                                                            \
    if ((T_) + 1 < ntiles) stageK((T_) + 1, (BUFC_) ^ 16384);                  \
    QKT_MASK(T_, BUFC_, SC0_, SC1_);                                           \
    finishPV(SP0_, SP1_, (BUFC_) ^ 16384);                                     \
    __syncthreads();                                                           \
    if ((T_) + 1 < ntiles) stageV((T_) + 1, (BUFC_) ^ 16384);                  \
  }

  f32x16 PA0, PA1, PB0, PB1;

  stageK(0, 0); stageV(0, 0);
  __syncthreads();

  stageK(1, 16384);
  QKT_MASK(0, 0, PA0, PA1);
  __syncthreads();
  stageV(1, 16384);

  for (int t = 1; t + 2 < ntiles; t += 2){
    STEP(t,     16384, PA0, PA1, PB0, PB1);
    STEP(t + 1, 0,     PB0, PB1, PA0, PA1);
  }
  STEP(ntiles - 1, 16384, PA0, PA1, PB0, PB1);
  finishPV(PB0, PB1, 16384);

#undef STEP
#undef QKT_MASK

  float inv = 1.0f / l_run;
  const int b = bh >> 4, h = bh & 15;
#pragma unroll
  for (int r = 0; r < 16; r++){
    int qlr = (r & 3) + 8 * (r >> 2) + 4 * hi;
    float ir = __shfl(inv, qlr);
    long rowbase = ((long)b * SEQ + (qbase + qlr)) * DM + h * HD;
#pragma unroll
    for (int d2 = 0; d2 < 4; d2++)
      ab[rowbase + d2 * 32 + lq] = f2b(acc[d2][r] * ir);
  }
}

extern "C" void kernel_launch(void* const* d_in, const int* in_sizes, int n_in,
                              void* d_out, int out_size, void* d_ws, size_t ws_size,
                              hipStream_t stream) {
  const float* x      = (const float*)d_in[0];
  const float* past_k = (const float*)d_in[1];
  const float* past_v = (const float*)d_in[2];
  const float* Wq     = (const float*)d_in[3];
  const float* Wk     = (const float*)d_in[4];
  const float* Wv     = (const float*)d_in[5];
  const float* Wo     = (const float*)d_in[6];

  float* out  = (float*)d_out;
  float* outk = out + 8388608;       // B*S*DM
  float* outv = out + 25165824;      // + B*NH*FULLS*HD

  char* ws = (char*)d_ws;
  u16* wqb = (u16*)ws;
  u16* wkb = (u16*)(ws + 8388608);
  u16* wvb = (u16*)(ws + 16777216);
  u16* wob = (u16*)(ws + 25165824);
  u16* xb  = (u16*)(ws + 33554432);
  u16* qb  = (u16*)(ws + 50331648);
  u16* kb  = (u16*)(ws + 67108864);
  u16* vtb = (u16*)(ws + 100663296);
  u16* ab  = xb;                     // alias: x consumed before attn writes

  k_conv5<<<2048, 256, 0, stream>>>(x, Wq, Wk, Wv, Wo, xb, wqb, wkb, wvb, wob);

  k_qkv_fused<<<512, 512, 0, stream>>>(xb, wqb, wkb, wvb,
                                       qb, kb, vtb, outk, outv,
                                       past_k, past_v);

  k_attn<<<512, 256, 0, stream>>>(qb, kb, vtb, ab);

  k_gemm_o8<<<256, 512, 0, stream>>>(ab, wob, out);
}